// Round 4
// baseline (514.373 us; speedup 1.0000x reference)
//
#include <hip/hip_runtime.h>

// NavAssignNet on MI355X — round 4.
//   - NEW: k_bigpass carries 16 prefetch WGs that stream the NEXT update's
//     weight panels into every XCD's L2 (update was HBM-latency-bound at 42us,
//     FETCH 4.7MB/dispatch with 1 wave/SIMD).
//   - k_update_mfma unchanged (3-term bf16 split, fp32-class accuracy).

typedef short bf16x8 __attribute__((ext_vector_type(8)));
typedef float f32x4 __attribute__((ext_vector_type(4)));

#define DEV static __device__ __forceinline__

DEV unsigned short f2bf(float x) {
    unsigned u = __float_as_uint(x);
    return (unsigned short)((u + 0x7fffu + ((u >> 16) & 1u)) >> 16);
}
DEV void split2(float v, unsigned short& hi, unsigned short& lo) {
    unsigned short h = f2bf(v);
    float fh = __uint_as_float(((unsigned)h) << 16);
    hi = h;
    lo = f2bf(v - fh);
}

// ---- 1. prep: edge_raw -> bf16 AND traw = mean over i, 512 WGs ----
__global__ __launch_bounds__(256) void k_prep(const float* __restrict__ edge,
                                              unsigned short* __restrict__ edge_bf,
                                              float* __restrict__ traw) {
    int wg = blockIdx.x;                 // 512 = b*64 + j
    int b = wg >> 6, j = wg & 63;
    int t = threadIdx.x;
    int d = t & 127, ih = t >> 7;        // ih: i-half
    float s = 0.f;
    long base = ((long)(b * 64 + ih * 32) * 64 + j) * 128 + d;
#pragma unroll 8
    for (int ii = 0; ii < 32; ++ii) {
        long idx = base + (long)ii * 8192;
        float v = edge[idx];
        s += v;
        edge_bf[idx] = f2bf(v);
    }
    __shared__ float part[128];
    if (ih == 1) part[d] = s;
    __syncthreads();
    if (ih == 0) traw[(b * 64 + j) * 128 + d] = (s + part[d]) * (1.f / 64.f);
}

// ---- 2. WcT[p][h][d] = (Wp @ Wb_p)^T (bf16), bc[p][h] = bp@Wb_p + b_msg ----
__global__ __launch_bounds__(256) void k_wc(const float* __restrict__ Wp,
                                            const float* __restrict__ bp,
                                            const float* __restrict__ W_r2t,
                                            const float* __restrict__ b_r2t,
                                            const float* __restrict__ W_t2r,
                                            const float* __restrict__ b_t2r,
                                            unsigned short* __restrict__ WcT,
                                            float* __restrict__ bc) {
    int blk = blockIdx.x;
    int h = threadIdx.x;
    if (blk < 768) {
        int p = blk >> 7, d = blk & 127, l = p >> 1;
        const float* Wb = ((p & 1) ? W_t2r : W_r2t) + l * 512 * 256 + 256 * 256;
        float acc = 0.f;
        for (int k = 0; k < 256; ++k) acc += Wp[d * 256 + k] * Wb[k * 256 + h];
        WcT[p * 32768 + h * 128 + d] = f2bf(acc);
    } else {
        int p = blk - 768, l = p >> 1;
        const float* Wb = ((p & 1) ? W_t2r : W_r2t) + l * 512 * 256 + 256 * 256;
        const float* bm = ((p & 1) ? b_t2r : b_r2t) + l * 256;
        float acc = bm[h];
        for (int k = 0; k < 256; ++k) acc += bp[k] * Wb[k * 256 + h];
        bc[p * 256 + h] = acc;
    }
}

// ---- 3. split: W^T hi/lo bf16 planes for update GEMMs ----
__global__ __launch_bounds__(256) void k_split(const float* __restrict__ W_pt,
                                               const float* __restrict__ W_pr,
                                               const float* __restrict__ W_t2r,
                                               const float* __restrict__ W_r2t,
                                               const float* __restrict__ Ws1,
                                               unsigned short* __restrict__ WTbig,
                                               unsigned short* __restrict__ WT2) {
    int blk = blockIdx.x, t = threadIdx.x;
    if (blk < 1536) {
        int mat = blk >> 8, h = blk & 255, l = mat >> 1;
        const float* W = ((mat & 1) ? W_pr : W_pt) + l * 512 * 256;
        unsigned short* dh = WTbig + mat * 262144 + h * 512;
        unsigned short* dl = dh + 131072;
        for (int k = t; k < 512; k += 256) {
            unsigned short hi, lo;
            split2(W[k * 256 + h], hi, lo);
            dh[k] = hi; dl[k] = lo;
        }
    } else {
        int m2 = blk - 1536, mat = m2 >> 8, h = m2 & 255;
        const float* W;
        if (mat == 6) W = Ws1 + 256 * 256;
        else if (mat == 5) W = Ws1;
        else if (mat & 1) W = W_r2t + ((mat >> 1) + 1) * 512 * 256;
        else W = W_t2r + (mat >> 1) * 512 * 256;
        unsigned short* dh = WT2 + mat * 131072 + h * 256;
        unsigned short* dl = dh + 65536;
        unsigned short hi, lo;
        split2(W[t * 256 + h], hi, lo);
        dh[t] = hi; dl[t] = lo;
    }
}

// ---- 4. proj: robot_h/target_h = X @ Wp + bp ; robot WGs also emit rWa0 ----
__global__ __launch_bounds__(256) void k_proj(const float* __restrict__ robot_raw,
                                              const float* __restrict__ traw,
                                              const float* __restrict__ Wp,
                                              const float* __restrict__ bp,
                                              const float* __restrict__ Wa0,
                                              float* __restrict__ robot_h,
                                              float* __restrict__ target_h,
                                              float* __restrict__ rWa) {
    int h = threadIdx.x;
    int r0 = blockIdx.x * 2;
    int robot = (r0 < 512);
    const float* in;
    float* out;
    if (robot) { in = robot_raw + r0 * 128; out = robot_h + r0 * 256; }
    else       { in = traw + (r0 - 512) * 128; out = target_h + (r0 - 512) * 256; }
    float a0 = 0, a1 = 0;
    for (int k = 0; k < 128; ++k) {
        float w = Wp[k * 256 + h];
        a0 += in[k] * w; a1 += in[128 + k] * w;
    }
    float b = bp[h];
    a0 += b; a1 += b;
    out[h] = a0; out[256 + h] = a1;

    __shared__ float yl[2][257];
    if (robot) { yl[0][h] = a0; yl[1][h] = a1; }
    __syncthreads();
    if (robot) {
        float c0 = 0, c1 = 0;
        for (int k = 0; k < 256; ++k) {
            float w = Wa0[k * 256 + h];
            c0 += yl[0][k] * w; c1 += yl[1][k] * w;
        }
        rWa[r0 * 256 + h] = c0; rWa[(r0 + 1) * 256 + h] = c1;
    }
}

// ---- 5. update via MFMA split-bf16: state = LN(state + [state;agg]@W + b); fused y@W2a (+ y@W2b) ----
// 32 WGs x 16 rows, 4 waves each covering 64 cols.
__global__ __launch_bounds__(256) void k_update_mfma(
        float* __restrict__ state, const float* __restrict__ agg,
        const unsigned short* __restrict__ WTm,   // [hi 256x512][lo 256x512]
        const float* __restrict__ bvec, const float* __restrict__ g, const float* __restrict__ be,
        const unsigned short* __restrict__ WT2a,  // [hi 256x256][lo 256x256]
        float* __restrict__ out2a,
        const unsigned short* __restrict__ WT2b, const float* __restrict__ b2b,
        float* __restrict__ out2b) {
    int r0 = blockIdx.x * 16;
    int t = threadIdx.x;
    int w = t >> 6, lane = t & 63;
    int c16 = lane & 15, kg = lane >> 4;
    int colbase = 64 * w + c16;

    __shared__ unsigned short Ahi[16 * 512];
    __shared__ unsigned short Alo[16 * 512];
    __shared__ unsigned short Yhi[16 * 256];
    __shared__ unsigned short Ylo[16 * 256];
    __shared__ float red[4][16][2];

    // stage A = [state | agg] rows r0..r0+15 as swizzled hi/lo bf16
    {
        int row = t & 15, kq = t >> 4;   // kq 0..15 -> 32 K-elems each
        const float* src = (kq < 8) ? (state + (r0 + row) * 256 + kq * 32)
                                    : (agg + (r0 + row) * 256 + (kq - 8) * 32);
#pragma unroll
        for (int blk = 0; blk < 4; ++blk) {
            float4 a = *(const float4*)(src + blk * 8);
            float4 b2 = *(const float4*)(src + blk * 8 + 4);
            unsigned short h[8], lo[8];
            split2(a.x, h[0], lo[0]); split2(a.y, h[1], lo[1]);
            split2(a.z, h[2], lo[2]); split2(a.w, h[3], lo[3]);
            split2(b2.x, h[4], lo[4]); split2(b2.y, h[5], lo[5]);
            split2(b2.z, h[6], lo[6]); split2(b2.w, h[7], lo[7]);
            int byte = row * 1024 + (kq * 32 + blk * 8) * 2;
            byte ^= (row & 7) << 4;
            ushort4* ph = (ushort4*)((char*)Ahi + byte);
            ph[0] = make_ushort4(h[0], h[1], h[2], h[3]);
            ph[1] = make_ushort4(h[4], h[5], h[6], h[7]);
            ushort4* pl = (ushort4*)((char*)Alo + byte);
            pl[0] = make_ushort4(lo[0], lo[1], lo[2], lo[3]);
            pl[1] = make_ushort4(lo[4], lo[5], lo[6], lo[7]);
        }
    }
    __syncthreads();

    // main GEMM: K=512, 3-term split
    f32x4 acc[4];
#pragma unroll
    for (int ni = 0; ni < 4; ++ni) acc[ni] = f32x4{0.f, 0.f, 0.f, 0.f};
    const unsigned short* Bh0 = WTm + colbase * 512 + kg * 8;
#pragma unroll 2
    for (int ks = 0; ks < 16; ++ks) {
        int ab = c16 * 1024 + ks * 64 + kg * 16;
        ab ^= (c16 & 7) << 4;
        bf16x8 ah = *(const bf16x8*)((const char*)Ahi + ab);
        bf16x8 al = *(const bf16x8*)((const char*)Alo + ab);
#pragma unroll
        for (int ni = 0; ni < 4; ++ni) {
            const unsigned short* p = Bh0 + ni * 16 * 512 + ks * 32;
            bf16x8 bh = *(const bf16x8*)p;
            bf16x8 bl = *(const bf16x8*)(p + 131072);
            acc[ni] = __builtin_amdgcn_mfma_f32_16x16x32_bf16(ah, bh, acc[ni], 0, 0, 0);
            acc[ni] = __builtin_amdgcn_mfma_f32_16x16x32_bf16(al, bh, acc[ni], 0, 0, 0);
            acc[ni] = __builtin_amdgcn_mfma_f32_16x16x32_bf16(ah, bl, acc[ni], 0, 0, 0);
        }
    }

    // residual + bias
    float x[4][4];
#pragma unroll
    for (int ni = 0; ni < 4; ++ni) {
        int col = colbase + 16 * ni;
        float bv = bvec[col];
#pragma unroll
        for (int r = 0; r < 4; ++r) {
            int row = kg * 4 + r;
            x[ni][r] = acc[ni][r] + state[(r0 + row) * 256 + col] + bv;
        }
    }

    // LN stats
    float s[4], q[4];
#pragma unroll
    for (int r = 0; r < 4; ++r) {
        s[r] = x[0][r] + x[1][r] + x[2][r] + x[3][r];
        q[r] = x[0][r] * x[0][r] + x[1][r] * x[1][r] + x[2][r] * x[2][r] + x[3][r] * x[3][r];
#pragma unroll
        for (int m = 1; m < 16; m <<= 1) {
            s[r] += __shfl_xor(s[r], m);
            q[r] += __shfl_xor(q[r], m);
        }
    }
    if (c16 == 0) {
#pragma unroll
        for (int r = 0; r < 4; ++r) {
            red[w][kg * 4 + r][0] = s[r];
            red[w][kg * 4 + r][1] = q[r];
        }
    }
    __syncthreads();
    float mr[4], rsr[4];
#pragma unroll
    for (int r = 0; r < 4; ++r) {
        int row = kg * 4 + r;
        float S = red[0][row][0] + red[1][row][0] + red[2][row][0] + red[3][row][0];
        float Q = red[0][row][1] + red[1][row][1] + red[2][row][1] + red[3][row][1];
        float m = S * (1.f / 256.f);
        float v = Q * (1.f / 256.f) - m * m;
        mr[r] = m;
        rsr[r] = rsqrtf(v + 1e-5f);
    }

    // y = LN(x): store to state + stage bf16 hi/lo into LDS (swizzled)
#pragma unroll
    for (int ni = 0; ni < 4; ++ni) {
        int col = colbase + 16 * ni;
        float gg = g[col], bb = be[col];
#pragma unroll
        for (int r = 0; r < 4; ++r) {
            int row = kg * 4 + r;
            float y = (x[ni][r] - mr[r]) * rsr[r] * gg + bb;
            state[(r0 + row) * 256 + col] = y;
            unsigned short yh, yl2;
            split2(y, yh, yl2);
            int byte = (row * 512 + col * 2) ^ ((row & 7) << 4);
            *(unsigned short*)((char*)Yhi + byte) = yh;
            *(unsigned short*)((char*)Ylo + byte) = yl2;
        }
    }
    __syncthreads();

    // fused GEMM(s): y @ W2a (-> out2a), optional y @ W2b + b2b (-> out2b transposed)
    f32x4 acc2[4], acc3[4];
#pragma unroll
    for (int ni = 0; ni < 4; ++ni) { acc2[ni] = f32x4{0.f, 0.f, 0.f, 0.f}; acc3[ni] = f32x4{0.f, 0.f, 0.f, 0.f}; }
    const unsigned short* B2h0 = WT2a + colbase * 256 + kg * 8;
    const unsigned short* B3h0 = WT2b ? (WT2b + colbase * 256 + kg * 8) : B2h0;
    int haveB = (WT2b != nullptr);
#pragma unroll 2
    for (int ks = 0; ks < 8; ++ks) {
        int ab = c16 * 512 + ks * 64 + kg * 16;
        ab ^= (c16 & 7) << 4;
        bf16x8 ah = *(const bf16x8*)((const char*)Yhi + ab);
        bf16x8 al = *(const bf16x8*)((const char*)Ylo + ab);
#pragma unroll
        for (int ni = 0; ni < 4; ++ni) {
            const unsigned short* p = B2h0 + ni * 16 * 256 + ks * 32;
            bf16x8 bh = *(const bf16x8*)p;
            bf16x8 bl = *(const bf16x8*)(p + 65536);
            acc2[ni] = __builtin_amdgcn_mfma_f32_16x16x32_bf16(ah, bh, acc2[ni], 0, 0, 0);
            acc2[ni] = __builtin_amdgcn_mfma_f32_16x16x32_bf16(al, bh, acc2[ni], 0, 0, 0);
            acc2[ni] = __builtin_amdgcn_mfma_f32_16x16x32_bf16(ah, bl, acc2[ni], 0, 0, 0);
            if (haveB) {
                const unsigned short* p3 = B3h0 + ni * 16 * 256 + ks * 32;
                bf16x8 bh3 = *(const bf16x8*)p3;
                bf16x8 bl3 = *(const bf16x8*)(p3 + 65536);
                acc3[ni] = __builtin_amdgcn_mfma_f32_16x16x32_bf16(ah, bh3, acc3[ni], 0, 0, 0);
                acc3[ni] = __builtin_amdgcn_mfma_f32_16x16x32_bf16(al, bh3, acc3[ni], 0, 0, 0);
                acc3[ni] = __builtin_amdgcn_mfma_f32_16x16x32_bf16(ah, bl3, acc3[ni], 0, 0, 0);
            }
        }
    }
#pragma unroll
    for (int ni = 0; ni < 4; ++ni) {
        int col = colbase + 16 * ni;
#pragma unroll
        for (int r = 0; r < 4; ++r) {
            int row = kg * 4 + r;
            out2a[(r0 + row) * 256 + col] = acc2[ni][r];
        }
    }
    if (haveB) {
#pragma unroll
        for (int ni = 0; ni < 4; ++ni) {
            int col = colbase + 16 * ni;
            float bb2 = b2b[col];
#pragma unroll
            for (int r = 0; r < 4; ++r) {
                int grow = r0 + kg * 4 + r;
                int b0 = grow >> 6, j = grow & 63;
                out2b[(b0 * 256 + col) * 64 + j] = acc3[ni][r] + bb2;
            }
        }
    }
}

// ---- 6. bigpass + L2 prefetch of next update's weights ----
// blockIdx < 16: prefetch WGs — stream prefA/prefB through this XCD's L2.
// blockIdx >= 16: compute WG (b,jj) as before.
__global__ __launch_bounds__(256) void k_bigpass(const unsigned short* __restrict__ edge_bf,
                                                 const unsigned short* __restrict__ WcT,
                                                 const float* __restrict__ bc,
                                                 const float* __restrict__ rowbias,
                                                 float* __restrict__ agg,
                                                 int mode,
                                                 const unsigned short* __restrict__ prefA,
                                                 int bytesA,
                                                 const unsigned short* __restrict__ prefB,
                                                 int bytesB) {
    if (blockIdx.x < 16) {
        // prefetch: pull weight panels into L2 (reads kept live, values unused)
        unsigned accp = 0;
        const uint4* pa = (const uint4*)prefA;
        int na = bytesA >> 4;
        for (int i = threadIdx.x; i < na; i += 256) {
            uint4 v = pa[i];
            accp ^= v.x ^ v.y ^ v.z ^ v.w;
        }
        const uint4* pb = (const uint4*)prefB;
        int nb = bytesB >> 4;
        for (int i = threadIdx.x; i < nb; i += 256) {
            uint4 v = pb[i];
            accp ^= v.x ^ v.y ^ v.z ^ v.w;
        }
        asm volatile("" :: "v"(accp));
        return;
    }
    int wg = blockIdx.x - 16;            // 512 = b*64 + jj
    int b = wg >> 6, jj = wg & 63;
    int w = threadIdx.x >> 6, lane = threadIdx.x & 63;
    int row16 = lane & 15, kgrp = lane >> 4;

    int rstride = (mode == 0) ? 8192 : 128;
    const unsigned short* A = edge_bf + b * 524288 + ((mode == 0) ? jj * 128 : jj * 8192);
    const unsigned short* Ap = A + row16 * rstride + 8 * kgrp;
    const unsigned short* Bp = WcT + (64 * w + row16) * 128 + 8 * kgrp;

    f32x4 acc[4][4];
#pragma unroll
    for (int mi = 0; mi < 4; ++mi)
#pragma unroll
        for (int ni = 0; ni < 4; ++ni) acc[mi][ni] = f32x4{0.f, 0.f, 0.f, 0.f};

#pragma unroll
    for (int kk = 0; kk < 4; ++kk) {
        bf16x8 av[4], bv[4];
#pragma unroll
        for (int mi = 0; mi < 4; ++mi)
            av[mi] = *(const bf16x8*)(Ap + mi * 16 * rstride + kk * 32);
#pragma unroll
        for (int ni = 0; ni < 4; ++ni)
            bv[ni] = *(const bf16x8*)(Bp + ni * 16 * 128 + kk * 32);
#pragma unroll
        for (int mi = 0; mi < 4; ++mi)
#pragma unroll
            for (int ni = 0; ni < 4; ++ni)
                acc[mi][ni] = __builtin_amdgcn_mfma_f32_16x16x32_bf16(av[mi], bv[ni], acc[mi][ni], 0, 0, 0);
    }

    const float* rb = rowbias + (b * 64) * 256;
    float colsum[4] = {0.f, 0.f, 0.f, 0.f};
#pragma unroll
    for (int ni = 0; ni < 4; ++ni) {
        int col = 64 * w + 16 * ni + row16;
        float bch = bc[col];
#pragma unroll
        for (int mi = 0; mi < 4; ++mi) {
            int rbase = 16 * mi + 4 * kgrp;
#pragma unroll
            for (int r = 0; r < 4; ++r) {
                float v = acc[mi][ni][r] + rb[(rbase + r) * 256 + col] + bch;
                colsum[ni] += fmaxf(v, 0.f);
            }
        }
    }
#pragma unroll
    for (int ni = 0; ni < 4; ++ni) {
        colsum[ni] += __shfl_xor(colsum[ni], 16);
        colsum[ni] += __shfl_xor(colsum[ni], 32);
    }
    if (kgrp == 0) {
        float* o = agg + (b * 64 + jj) * 256 + 64 * w + row16;
#pragma unroll
        for (int ni = 0; ni < 4; ++ni) o[16 * ni] = colsum[ni] * (1.f / 64.f);
    }
}

// ---- 7. scores ----
__global__ __launch_bounds__(256) void k_scores(const float* __restrict__ rS,
                                                const float* __restrict__ tST,
                                                const float* __restrict__ Ws2,
                                                const float* __restrict__ bs2,
                                                float* __restrict__ scores) {
    int t = blockIdx.x * 256 + threadIdx.x;          // 32768
    int j = t & 63, i = (t >> 6) & 63, b = t >> 12;
    const float* rs = rS + (b * 64 + i) * 256;
    const float* ts = tST + b * 256 * 64 + j;
    float acc = bs2[0];
    for (int h = 0; h < 256; ++h)
        acc += fmaxf(rs[h] + ts[h * 64], 0.f) * Ws2[h];
    scores[t] = acc;
}

// ---- 8. sinkhorn: register-resident ----
__global__ __launch_bounds__(256) void k_sinkhorn(const float* __restrict__ scores,
                                                  float* __restrict__ probs) {
    int b = blockIdx.x;
    int t = threadIdx.x;
    int j = t & 63, rg = t >> 6;
    float v[16];
    const float* src = scores + b * 4096 + rg * 1024 + j;
#pragma unroll
    for (int k = 0; k < 16; ++k) v[k] = src[k * 64];

    __shared__ float lm_s[4][64];
    __shared__ float ps_s[4][64];

    for (int it = 0; it < 10; ++it) {
#pragma unroll
        for (int k = 0; k < 16; ++k) {
            float m = v[k];
#pragma unroll
            for (int s = 1; s < 64; s <<= 1) m = fmaxf(m, __shfl_xor(m, s));
            float e = __expf(v[k] - m), ss = e;
#pragma unroll
            for (int s = 1; s < 64; s <<= 1) ss += __shfl_xor(ss, s);
            v[k] -= m + __logf(ss);
        }
        float lm = v[0];
#pragma unroll
        for (int k = 1; k < 16; ++k) lm = fmaxf(lm, v[k]);
        float ps = 0.f;
#pragma unroll
        for (int k = 0; k < 16; ++k) ps += __expf(v[k] - lm);
        lm_s[rg][j] = lm; ps_s[rg][j] = ps;
        __syncthreads();
        float m0 = lm_s[0][j], m1 = lm_s[1][j], m2 = lm_s[2][j], m3 = lm_s[3][j];
        float M = fmaxf(fmaxf(m0, m1), fmaxf(m2, m3));
        float S = ps_s[0][j] * __expf(m0 - M) + ps_s[1][j] * __expf(m1 - M)
                + ps_s[2][j] * __expf(m2 - M) + ps_s[3][j] * __expf(m3 - M);
        float lse = M + __logf(S);
#pragma unroll
        for (int k = 0; k < 16; ++k) v[k] -= lse;
        __syncthreads();
    }
    float* dst = probs + b * 4096 + rg * 1024 + j;
#pragma unroll
    for (int k = 0; k < 16; ++k) dst[k * 64] = __expf(v[k]);
}

extern "C" void kernel_launch(void* const* d_in, const int* in_sizes, int n_in,
                              void* d_out, int out_size, void* d_ws, size_t ws_size,
                              hipStream_t stream) {
    const float* robot_raw = (const float*)d_in[0];
    const float* edge_raw  = (const float*)d_in[1];
    const float* Wp    = (const float*)d_in[2];
    const float* bp    = (const float*)d_in[3];
    const float* W_r2t = (const float*)d_in[4];
    const float* b_r2t = (const float*)d_in[5];
    const float* W_pt  = (const float*)d_in[6];
    const float* b_pt  = (const float*)d_in[7];
    const float* g_t   = (const float*)d_in[8];
    const float* be_t  = (const float*)d_in[9];
    const float* W_t2r = (const float*)d_in[10];
    const float* b_t2r = (const float*)d_in[11];
    const float* W_pr  = (const float*)d_in[12];
    const float* b_pr  = (const float*)d_in[13];
    const float* g_r   = (const float*)d_in[14];
    const float* be_r  = (const float*)d_in[15];
    const float* Ws1   = (const float*)d_in[16];
    const float* bs1   = (const float*)d_in[17];
    const float* Ws2   = (const float*)d_in[18];
    const float* bs2   = (const float*)d_in[19];

    char* ws = (char*)d_ws;
    unsigned short* edge_bf = (unsigned short*)(ws);            // 8,388,608
    float* traw     = (float*)(ws + 8388608);                   //   262,144
    float* robot_h  = (float*)(ws + 8650752);                   //   524,288
    float* target_h = (float*)(ws + 9175040);                   //   524,288
    unsigned short* WcT = (unsigned short*)(ws + 9699328);      //   393,216
    float* bc       = (float*)(ws + 10092544);                  //     6,144
    float* rWa      = (float*)(ws + 10098688);                  //   524,288
    float* tWa      = (float*)(ws + 10622976);                  //   524,288
    float* agg      = (float*)(ws + 11147264);                  //   524,288
    float* rS       = (float*)(ws + 11671552);                  //   524,288
    float* tST      = (float*)(ws + 12195840);                  //   524,288
    unsigned short* WTbig = (unsigned short*)(ws + 12720128);   // 3,145,728
    unsigned short* WT2   = (unsigned short*)(ws + 15865856);   // 1,835,008

    float* out    = (float*)d_out;
    float* probs  = out;            // output 0
    float* scores = out + 32768;    // output 1

    hipLaunchKernelGGL(k_prep, dim3(512), dim3(256), 0, stream, edge_raw, edge_bf, traw);
    hipLaunchKernelGGL(k_wc, dim3(774), dim3(256), 0, stream, Wp, bp, W_r2t, b_r2t, W_t2r, b_t2r, WcT, bc);
    hipLaunchKernelGGL(k_split, dim3(3328), dim3(256), 0, stream, W_pt, W_pr, W_t2r, W_r2t, Ws1, WTbig, WT2);
    hipLaunchKernelGGL(k_proj, dim3(512), dim3(256), 0, stream,
                       robot_raw, traw, Wp, bp, W_r2t, robot_h, target_h, rWa);

    for (int l = 0; l < 3; ++l) {
        // r2t bigpass + prefetch of the target-update weights
        {
            const unsigned short* pA = WTbig + (2 * l) * 262144;       // hi+lo, 512KB
            const unsigned short* pB = WT2 + (2 * l) * 131072;         // WT2a (+beyond for l==2)
            int bB = (l == 2) ? (3 * 262144) : 262144;                 // l==2: mats 4..6 (covers W2b too)
            hipLaunchKernelGGL(k_bigpass, dim3(528), dim3(256), 0, stream,
                               edge_bf, WcT + (2 * l) * 32768, bc + (2 * l) * 256, rWa, agg, 0,
                               pA, 524288, pB, bB);
        }
        const unsigned short* W2b = (l == 2) ? (WT2 + 6 * 131072) : nullptr;
        const float* b2b = (l == 2) ? bs1 : nullptr;
        float* o2b = (l == 2) ? tST : nullptr;
        hipLaunchKernelGGL(k_update_mfma, dim3(32), dim3(256), 0, stream,
                           target_h, agg, WTbig + (2 * l) * 262144,
                           b_pt + l * 256, g_t + l * 256, be_t + l * 256,
                           WT2 + (2 * l) * 131072, tWa, W2b, b2b, o2b);
        // t2r bigpass + prefetch of the robot-update weights
        {
            const unsigned short* pA = WTbig + (2 * l + 1) * 262144;
            int m2 = (l < 2) ? (2 * l + 1) : 5;
            const unsigned short* pB = WT2 + m2 * 131072;
            hipLaunchKernelGGL(k_bigpass, dim3(528), dim3(256), 0, stream,
                               edge_bf, WcT + (2 * l + 1) * 32768, bc + (2 * l + 1) * 256, tWa, agg, 1,
                               pA, 524288, pB, 262144);
        }
        const unsigned short* W2a = (l < 2) ? (WT2 + (2 * l + 1) * 131072) : (WT2 + 5 * 131072);
        float* o2a = (l < 2) ? rWa : rS;
        hipLaunchKernelGGL(k_update_mfma, dim3(32), dim3(256), 0, stream,
                           robot_h, agg, WTbig + (2 * l + 1) * 262144,
                           b_pr + l * 256, g_r + l * 256, be_r + l * 256,
                           W2a, o2a, (const unsigned short*)nullptr, (const float*)nullptr, (float*)nullptr);
    }

    hipLaunchKernelGGL(k_scores, dim3(128), dim3(256), 0, stream, rS, tST, Ws2, bs2, scores);
    hipLaunchKernelGGL(k_sinkhorn, dim3(8), dim3(256), 0, stream, scores, probs);
}

// Round 5
// 384.024 us; speedup vs baseline: 1.3394x; 1.3394x over previous
//
#include <hip/hip_runtime.h>

// NavAssignNet on MI355X — round 5.
//   - prefetch distributed over all 512 bigpass compute WGs (round 4's 16
//     dedicated prefetch WGs were issue-rate-bound at 33us and became the
//     kernel's critical path).
//   - k_update_mfma: 512 threads / 8 waves (32 cols each) to double the
//     VMEM issue rate (was load-issue-bound: 786KB/WG via 4 waves ~ 20us).

typedef short bf16x8 __attribute__((ext_vector_type(8)));
typedef float f32x4 __attribute__((ext_vector_type(4)));

#define DEV static __device__ __forceinline__

DEV unsigned short f2bf(float x) {
    unsigned u = __float_as_uint(x);
    return (unsigned short)((u + 0x7fffu + ((u >> 16) & 1u)) >> 16);
}
DEV void split2(float v, unsigned short& hi, unsigned short& lo) {
    unsigned short h = f2bf(v);
    float fh = __uint_as_float(((unsigned)h) << 16);
    hi = h;
    lo = f2bf(v - fh);
}

// ---- 1. prep: edge_raw -> bf16 AND traw = mean over i, 512 WGs ----
__global__ __launch_bounds__(256) void k_prep(const float* __restrict__ edge,
                                              unsigned short* __restrict__ edge_bf,
                                              float* __restrict__ traw) {
    int wg = blockIdx.x;                 // 512 = b*64 + j
    int b = wg >> 6, j = wg & 63;
    int t = threadIdx.x;
    int d = t & 127, ih = t >> 7;        // ih: i-half
    float s = 0.f;
    long base = ((long)(b * 64 + ih * 32) * 64 + j) * 128 + d;
#pragma unroll 8
    for (int ii = 0; ii < 32; ++ii) {
        long idx = base + (long)ii * 8192;
        float v = edge[idx];
        s += v;
        edge_bf[idx] = f2bf(v);
    }
    __shared__ float part[128];
    if (ih == 1) part[d] = s;
    __syncthreads();
    if (ih == 0) traw[(b * 64 + j) * 128 + d] = (s + part[d]) * (1.f / 64.f);
}

// ---- 2. WcT[p][h][d] = (Wp @ Wb_p)^T (bf16), bc[p][h] = bp@Wb_p + b_msg ----
__global__ __launch_bounds__(256) void k_wc(const float* __restrict__ Wp,
                                            const float* __restrict__ bp,
                                            const float* __restrict__ W_r2t,
                                            const float* __restrict__ b_r2t,
                                            const float* __restrict__ W_t2r,
                                            const float* __restrict__ b_t2r,
                                            unsigned short* __restrict__ WcT,
                                            float* __restrict__ bc) {
    int blk = blockIdx.x;
    int h = threadIdx.x;
    if (blk < 768) {
        int p = blk >> 7, d = blk & 127, l = p >> 1;
        const float* Wb = ((p & 1) ? W_t2r : W_r2t) + l * 512 * 256 + 256 * 256;
        float acc = 0.f;
        for (int k = 0; k < 256; ++k) acc += Wp[d * 256 + k] * Wb[k * 256 + h];
        WcT[p * 32768 + h * 128 + d] = f2bf(acc);
    } else {
        int p = blk - 768, l = p >> 1;
        const float* Wb = ((p & 1) ? W_t2r : W_r2t) + l * 512 * 256 + 256 * 256;
        const float* bm = ((p & 1) ? b_t2r : b_r2t) + l * 256;
        float acc = bm[h];
        for (int k = 0; k < 256; ++k) acc += bp[k] * Wb[k * 256 + h];
        bc[p * 256 + h] = acc;
    }
}

// ---- 3. split: W^T hi/lo bf16 planes for update GEMMs ----
__global__ __launch_bounds__(256) void k_split(const float* __restrict__ W_pt,
                                               const float* __restrict__ W_pr,
                                               const float* __restrict__ W_t2r,
                                               const float* __restrict__ W_r2t,
                                               const float* __restrict__ Ws1,
                                               unsigned short* __restrict__ WTbig,
                                               unsigned short* __restrict__ WT2) {
    int blk = blockIdx.x, t = threadIdx.x;
    if (blk < 1536) {
        int mat = blk >> 8, h = blk & 255, l = mat >> 1;
        const float* W = ((mat & 1) ? W_pr : W_pt) + l * 512 * 256;
        unsigned short* dh = WTbig + mat * 262144 + h * 512;
        unsigned short* dl = dh + 131072;
        for (int k = t; k < 512; k += 256) {
            unsigned short hi, lo;
            split2(W[k * 256 + h], hi, lo);
            dh[k] = hi; dl[k] = lo;
        }
    } else {
        int m2 = blk - 1536, mat = m2 >> 8, h = m2 & 255;
        const float* W;
        if (mat == 6) W = Ws1 + 256 * 256;
        else if (mat == 5) W = Ws1;
        else if (mat & 1) W = W_r2t + ((mat >> 1) + 1) * 512 * 256;
        else W = W_t2r + (mat >> 1) * 512 * 256;
        unsigned short* dh = WT2 + mat * 131072 + h * 256;
        unsigned short* dl = dh + 65536;
        unsigned short hi, lo;
        split2(W[t * 256 + h], hi, lo);
        dh[t] = hi; dl[t] = lo;
    }
}

// ---- 4. proj: robot_h/target_h = X @ Wp + bp ; robot WGs also emit rWa0 ----
__global__ __launch_bounds__(256) void k_proj(const float* __restrict__ robot_raw,
                                              const float* __restrict__ traw,
                                              const float* __restrict__ Wp,
                                              const float* __restrict__ bp,
                                              const float* __restrict__ Wa0,
                                              float* __restrict__ robot_h,
                                              float* __restrict__ target_h,
                                              float* __restrict__ rWa) {
    int h = threadIdx.x;
    int r0 = blockIdx.x * 2;
    int robot = (r0 < 512);
    const float* in;
    float* out;
    if (robot) { in = robot_raw + r0 * 128; out = robot_h + r0 * 256; }
    else       { in = traw + (r0 - 512) * 128; out = target_h + (r0 - 512) * 256; }
    float a0 = 0, a1 = 0;
    for (int k = 0; k < 128; ++k) {
        float w = Wp[k * 256 + h];
        a0 += in[k] * w; a1 += in[128 + k] * w;
    }
    float b = bp[h];
    a0 += b; a1 += b;
    out[h] = a0; out[256 + h] = a1;

    __shared__ float yl[2][257];
    if (robot) { yl[0][h] = a0; yl[1][h] = a1; }
    __syncthreads();
    if (robot) {
        float c0 = 0, c1 = 0;
        for (int k = 0; k < 256; ++k) {
            float w = Wa0[k * 256 + h];
            c0 += yl[0][k] * w; c1 += yl[1][k] * w;
        }
        rWa[r0 * 256 + h] = c0; rWa[(r0 + 1) * 256 + h] = c1;
    }
}

// ---- 5. update via MFMA split-bf16, 512 threads / 8 waves (32 cols each) ----
// state = LN(state + [state;agg]@W + b); fused y@W2a (+ y@W2b transposed)
__global__ __launch_bounds__(512) void k_update_mfma(
        float* __restrict__ state, const float* __restrict__ agg,
        const unsigned short* __restrict__ WTm,   // [hi 256x512][lo 256x512]
        const float* __restrict__ bvec, const float* __restrict__ g, const float* __restrict__ be,
        const unsigned short* __restrict__ WT2a,  // [hi 256x256][lo 256x256]
        float* __restrict__ out2a,
        const unsigned short* __restrict__ WT2b, const float* __restrict__ b2b,
        float* __restrict__ out2b) {
    int r0 = blockIdx.x * 16;
    int t = threadIdx.x;
    int w = t >> 6, lane = t & 63;
    int c16 = lane & 15, kg = lane >> 4;
    int colbase = 32 * w + c16;

    __shared__ unsigned short Ahi[16 * 512];
    __shared__ unsigned short Alo[16 * 512];
    __shared__ unsigned short Yhi[16 * 256];
    __shared__ unsigned short Ylo[16 * 256];
    __shared__ float red[8][16][2];

    // stage A = [state | agg] rows r0..r0+15 as swizzled hi/lo bf16
    {
        int row = t & 15, kq = t >> 4;   // kq 0..31 -> 16 K-elems each
        const float* src = (kq < 16) ? (state + (r0 + row) * 256 + kq * 16)
                                     : (agg + (r0 + row) * 256 + (kq - 16) * 16);
#pragma unroll
        for (int blk = 0; blk < 2; ++blk) {
            float4 a = *(const float4*)(src + blk * 8);
            float4 b2 = *(const float4*)(src + blk * 8 + 4);
            unsigned short h[8], lo[8];
            split2(a.x, h[0], lo[0]); split2(a.y, h[1], lo[1]);
            split2(a.z, h[2], lo[2]); split2(a.w, h[3], lo[3]);
            split2(b2.x, h[4], lo[4]); split2(b2.y, h[5], lo[5]);
            split2(b2.z, h[6], lo[6]); split2(b2.w, h[7], lo[7]);
            int byte = row * 1024 + (kq * 16 + blk * 8) * 2;
            byte ^= (row & 7) << 4;
            ushort4* ph = (ushort4*)((char*)Ahi + byte);
            ph[0] = make_ushort4(h[0], h[1], h[2], h[3]);
            ph[1] = make_ushort4(h[4], h[5], h[6], h[7]);
            ushort4* pl = (ushort4*)((char*)Alo + byte);
            pl[0] = make_ushort4(lo[0], lo[1], lo[2], lo[3]);
            pl[1] = make_ushort4(lo[4], lo[5], lo[6], lo[7]);
        }
    }
    __syncthreads();

    // main GEMM: K=512, 3-term split, 2 col-tiles per wave
    f32x4 acc[2];
#pragma unroll
    for (int ni = 0; ni < 2; ++ni) acc[ni] = f32x4{0.f, 0.f, 0.f, 0.f};
    const unsigned short* Bh0 = WTm + colbase * 512 + kg * 8;
#pragma unroll 2
    for (int ks = 0; ks < 16; ++ks) {
        int ab = c16 * 1024 + ks * 64 + kg * 16;
        ab ^= (c16 & 7) << 4;
        bf16x8 ah = *(const bf16x8*)((const char*)Ahi + ab);
        bf16x8 al = *(const bf16x8*)((const char*)Alo + ab);
#pragma unroll
        for (int ni = 0; ni < 2; ++ni) {
            const unsigned short* p = Bh0 + ni * 16 * 512 + ks * 32;
            bf16x8 bh = *(const bf16x8*)p;
            bf16x8 bl = *(const bf16x8*)(p + 131072);
            acc[ni] = __builtin_amdgcn_mfma_f32_16x16x32_bf16(ah, bh, acc[ni], 0, 0, 0);
            acc[ni] = __builtin_amdgcn_mfma_f32_16x16x32_bf16(al, bh, acc[ni], 0, 0, 0);
            acc[ni] = __builtin_amdgcn_mfma_f32_16x16x32_bf16(ah, bl, acc[ni], 0, 0, 0);
        }
    }

    // residual + bias
    float x[2][4];
#pragma unroll
    for (int ni = 0; ni < 2; ++ni) {
        int col = colbase + 16 * ni;
        float bv = bvec[col];
#pragma unroll
        for (int r = 0; r < 4; ++r) {
            int row = kg * 4 + r;
            x[ni][r] = acc[ni][r] + state[(r0 + row) * 256 + col] + bv;
        }
    }

    // LN stats
    float s[4], q[4];
#pragma unroll
    for (int r = 0; r < 4; ++r) {
        s[r] = x[0][r] + x[1][r];
        q[r] = x[0][r] * x[0][r] + x[1][r] * x[1][r];
#pragma unroll
        for (int m = 1; m < 16; m <<= 1) {
            s[r] += __shfl_xor(s[r], m);
            q[r] += __shfl_xor(q[r], m);
        }
    }
    if (c16 == 0) {
#pragma unroll
        for (int r = 0; r < 4; ++r) {
            red[w][kg * 4 + r][0] = s[r];
            red[w][kg * 4 + r][1] = q[r];
        }
    }
    __syncthreads();
    float mr[4], rsr[4];
#pragma unroll
    for (int r = 0; r < 4; ++r) {
        int row = kg * 4 + r;
        float S = 0.f, Q = 0.f;
#pragma unroll
        for (int w2 = 0; w2 < 8; ++w2) { S += red[w2][row][0]; Q += red[w2][row][1]; }
        float m = S * (1.f / 256.f);
        float v = Q * (1.f / 256.f) - m * m;
        mr[r] = m;
        rsr[r] = rsqrtf(v + 1e-5f);
    }

    // y = LN(x): store to state + stage bf16 hi/lo into LDS (swizzled)
#pragma unroll
    for (int ni = 0; ni < 2; ++ni) {
        int col = colbase + 16 * ni;
        float gg = g[col], bb = be[col];
#pragma unroll
        for (int r = 0; r < 4; ++r) {
            int row = kg * 4 + r;
            float y = (x[ni][r] - mr[r]) * rsr[r] * gg + bb;
            state[(r0 + row) * 256 + col] = y;
            unsigned short yh, yl2;
            split2(y, yh, yl2);
            int byte = (row * 512 + col * 2) ^ ((row & 7) << 4);
            *(unsigned short*)((char*)Yhi + byte) = yh;
            *(unsigned short*)((char*)Ylo + byte) = yl2;
        }
    }
    __syncthreads();

    // fused GEMM(s): y @ W2a (-> out2a), optional y @ W2b + b2b (-> out2b transposed)
    f32x4 acc2[2], acc3[2];
#pragma unroll
    for (int ni = 0; ni < 2; ++ni) { acc2[ni] = f32x4{0.f, 0.f, 0.f, 0.f}; acc3[ni] = f32x4{0.f, 0.f, 0.f, 0.f}; }
    const unsigned short* B2h0 = WT2a + colbase * 256 + kg * 8;
    const unsigned short* B3h0 = WT2b ? (WT2b + colbase * 256 + kg * 8) : B2h0;
    int haveB = (WT2b != nullptr);
#pragma unroll 2
    for (int ks = 0; ks < 8; ++ks) {
        int ab = c16 * 512 + ks * 64 + kg * 16;
        ab ^= (c16 & 7) << 4;
        bf16x8 ah = *(const bf16x8*)((const char*)Yhi + ab);
        bf16x8 al = *(const bf16x8*)((const char*)Ylo + ab);
#pragma unroll
        for (int ni = 0; ni < 2; ++ni) {
            const unsigned short* p = B2h0 + ni * 16 * 256 + ks * 32;
            bf16x8 bh = *(const bf16x8*)p;
            bf16x8 bl = *(const bf16x8*)(p + 65536);
            acc2[ni] = __builtin_amdgcn_mfma_f32_16x16x32_bf16(ah, bh, acc2[ni], 0, 0, 0);
            acc2[ni] = __builtin_amdgcn_mfma_f32_16x16x32_bf16(al, bh, acc2[ni], 0, 0, 0);
            acc2[ni] = __builtin_amdgcn_mfma_f32_16x16x32_bf16(ah, bl, acc2[ni], 0, 0, 0);
            if (haveB) {
                const unsigned short* p3 = B3h0 + ni * 16 * 256 + ks * 32;
                bf16x8 bh3 = *(const bf16x8*)p3;
                bf16x8 bl3 = *(const bf16x8*)(p3 + 65536);
                acc3[ni] = __builtin_amdgcn_mfma_f32_16x16x32_bf16(ah, bh3, acc3[ni], 0, 0, 0);
                acc3[ni] = __builtin_amdgcn_mfma_f32_16x16x32_bf16(al, bh3, acc3[ni], 0, 0, 0);
                acc3[ni] = __builtin_amdgcn_mfma_f32_16x16x32_bf16(ah, bl3, acc3[ni], 0, 0, 0);
            }
        }
    }
#pragma unroll
    for (int ni = 0; ni < 2; ++ni) {
        int col = colbase + 16 * ni;
#pragma unroll
        for (int r = 0; r < 4; ++r) {
            int row = kg * 4 + r;
            out2a[(r0 + row) * 256 + col] = acc2[ni][r];
        }
    }
    if (haveB) {
#pragma unroll
        for (int ni = 0; ni < 2; ++ni) {
            int col = colbase + 16 * ni;
            float bb2 = b2b[col];
#pragma unroll
            for (int r = 0; r < 4; ++r) {
                int grow = r0 + kg * 4 + r;
                int b0 = grow >> 6, j = grow & 63;
                out2b[(b0 * 256 + col) * 64 + j] = acc3[ni][r] + bb2;
            }
        }
    }
}

// ---- 6. bigpass + distributed L2 prefetch of next update's weights ----
// Each compute WG prefetches a 1/64 slice at its tail (slice = (bid>>3)&63,
// so all 64 slices land on every XCD under round-robin bid->XCD mapping).
__global__ __launch_bounds__(256) void k_bigpass(const unsigned short* __restrict__ edge_bf,
                                                 const unsigned short* __restrict__ WcT,
                                                 const float* __restrict__ bc,
                                                 const float* __restrict__ rowbias,
                                                 float* __restrict__ agg,
                                                 int mode,
                                                 const unsigned short* __restrict__ prefA,
                                                 int bytesA,
                                                 const unsigned short* __restrict__ prefB,
                                                 int bytesB) {
    int wg = blockIdx.x;                 // 512 = b*64 + jj
    int b = wg >> 6, jj = wg & 63;
    int w = threadIdx.x >> 6, lane = threadIdx.x & 63;
    int row16 = lane & 15, kgrp = lane >> 4;

    int rstride = (mode == 0) ? 8192 : 128;
    const unsigned short* A = edge_bf + b * 524288 + ((mode == 0) ? jj * 128 : jj * 8192);
    const unsigned short* Ap = A + row16 * rstride + 8 * kgrp;
    const unsigned short* Bp = WcT + (64 * w + row16) * 128 + 8 * kgrp;

    f32x4 acc[4][4];
#pragma unroll
    for (int mi = 0; mi < 4; ++mi)
#pragma unroll
        for (int ni = 0; ni < 4; ++ni) acc[mi][ni] = f32x4{0.f, 0.f, 0.f, 0.f};

#pragma unroll
    for (int kk = 0; kk < 4; ++kk) {
        bf16x8 av[4], bv[4];
#pragma unroll
        for (int mi = 0; mi < 4; ++mi)
            av[mi] = *(const bf16x8*)(Ap + mi * 16 * rstride + kk * 32);
#pragma unroll
        for (int ni = 0; ni < 4; ++ni)
            bv[ni] = *(const bf16x8*)(Bp + ni * 16 * 128 + kk * 32);
#pragma unroll
        for (int mi = 0; mi < 4; ++mi)
#pragma unroll
            for (int ni = 0; ni < 4; ++ni)
                acc[mi][ni] = __builtin_amdgcn_mfma_f32_16x16x32_bf16(av[mi], bv[ni], acc[mi][ni], 0, 0, 0);
    }

    const float* rb = rowbias + (b * 64) * 256;
    float colsum[4] = {0.f, 0.f, 0.f, 0.f};
#pragma unroll
    for (int ni = 0; ni < 4; ++ni) {
        int col = 64 * w + 16 * ni + row16;
        float bch = bc[col];
#pragma unroll
        for (int mi = 0; mi < 4; ++mi) {
            int rbase = 16 * mi + 4 * kgrp;
#pragma unroll
            for (int r = 0; r < 4; ++r) {
                float v = acc[mi][ni][r] + rb[(rbase + r) * 256 + col] + bch;
                colsum[ni] += fmaxf(v, 0.f);
            }
        }
    }
#pragma unroll
    for (int ni = 0; ni < 4; ++ni) {
        colsum[ni] += __shfl_xor(colsum[ni], 16);
        colsum[ni] += __shfl_xor(colsum[ni], 32);
    }
    if (kgrp == 0) {
        float* o = agg + (b * 64 + jj) * 256 + 64 * w + row16;
#pragma unroll
        for (int ni = 0; ni < 4; ++ni) o[16 * ni] = colsum[ni] * (1.f / 64.f);
    }

    // tail prefetch: this WG's 1/64 slice of the next update's weight panels
    unsigned accp = 0;
    int s = (blockIdx.x >> 3) & 63;
    {
        int na = bytesA >> 10;           // uint4 per slice (= bytes/64/16)
        const uint4* pa = (const uint4*)prefA + (long)s * na;
        for (int i = threadIdx.x; i < na; i += 256) {
            uint4 v = pa[i];
            accp ^= v.x ^ v.y ^ v.z ^ v.w;
        }
        int nb = bytesB >> 10;
        const uint4* pb = (const uint4*)prefB + (long)s * nb;
        for (int i = threadIdx.x; i < nb; i += 256) {
            uint4 v = pb[i];
            accp ^= v.x ^ v.y ^ v.z ^ v.w;
        }
    }
    asm volatile("" :: "v"(accp));
}

// ---- 7. scores ----
__global__ __launch_bounds__(256) void k_scores(const float* __restrict__ rS,
                                                const float* __restrict__ tST,
                                                const float* __restrict__ Ws2,
                                                const float* __restrict__ bs2,
                                                float* __restrict__ scores) {
    int t = blockIdx.x * 256 + threadIdx.x;          // 32768
    int j = t & 63, i = (t >> 6) & 63, b = t >> 12;
    const float* rs = rS + (b * 64 + i) * 256;
    const float* ts = tST + b * 256 * 64 + j;
    float acc = bs2[0];
    for (int h = 0; h < 256; ++h)
        acc += fmaxf(rs[h] + ts[h * 64], 0.f) * Ws2[h];
    scores[t] = acc;
}

// ---- 8. sinkhorn: register-resident ----
__global__ __launch_bounds__(256) void k_sinkhorn(const float* __restrict__ scores,
                                                  float* __restrict__ probs) {
    int b = blockIdx.x;
    int t = threadIdx.x;
    int j = t & 63, rg = t >> 6;
    float v[16];
    const float* src = scores + b * 4096 + rg * 1024 + j;
#pragma unroll
    for (int k = 0; k < 16; ++k) v[k] = src[k * 64];

    __shared__ float lm_s[4][64];
    __shared__ float ps_s[4][64];

    for (int it = 0; it < 10; ++it) {
#pragma unroll
        for (int k = 0; k < 16; ++k) {
            float m = v[k];
#pragma unroll
            for (int s = 1; s < 64; s <<= 1) m = fmaxf(m, __shfl_xor(m, s));
            float e = __expf(v[k] - m), ss = e;
#pragma unroll
            for (int s = 1; s < 64; s <<= 1) ss += __shfl_xor(ss, s);
            v[k] -= m + __logf(ss);
        }
        float lm = v[0];
#pragma unroll
        for (int k = 1; k < 16; ++k) lm = fmaxf(lm, v[k]);
        float ps = 0.f;
#pragma unroll
        for (int k = 0; k < 16; ++k) ps += __expf(v[k] - lm);
        lm_s[rg][j] = lm; ps_s[rg][j] = ps;
        __syncthreads();
        float m0 = lm_s[0][j], m1 = lm_s[1][j], m2 = lm_s[2][j], m3 = lm_s[3][j];
        float M = fmaxf(fmaxf(m0, m1), fmaxf(m2, m3));
        float S = ps_s[0][j] * __expf(m0 - M) + ps_s[1][j] * __expf(m1 - M)
                + ps_s[2][j] * __expf(m2 - M) + ps_s[3][j] * __expf(m3 - M);
        float lse = M + __logf(S);
#pragma unroll
        for (int k = 0; k < 16; ++k) v[k] -= lse;
        __syncthreads();
    }
    float* dst = probs + b * 4096 + rg * 1024 + j;
#pragma unroll
    for (int k = 0; k < 16; ++k) dst[k * 64] = __expf(v[k]);
}

extern "C" void kernel_launch(void* const* d_in, const int* in_sizes, int n_in,
                              void* d_out, int out_size, void* d_ws, size_t ws_size,
                              hipStream_t stream) {
    const float* robot_raw = (const float*)d_in[0];
    const float* edge_raw  = (const float*)d_in[1];
    const float* Wp    = (const float*)d_in[2];
    const float* bp    = (const float*)d_in[3];
    const float* W_r2t = (const float*)d_in[4];
    const float* b_r2t = (const float*)d_in[5];
    const float* W_pt  = (const float*)d_in[6];
    const float* b_pt  = (const float*)d_in[7];
    const float* g_t   = (const float*)d_in[8];
    const float* be_t  = (const float*)d_in[9];
    const float* W_t2r = (const float*)d_in[10];
    const float* b_t2r = (const float*)d_in[11];
    const float* W_pr  = (const float*)d_in[12];
    const float* b_pr  = (const float*)d_in[13];
    const float* g_r   = (const float*)d_in[14];
    const float* be_r  = (const float*)d_in[15];
    const float* Ws1   = (const float*)d_in[16];
    const float* bs1   = (const float*)d_in[17];
    const float* Ws2   = (const float*)d_in[18];
    const float* bs2   = (const float*)d_in[19];

    char* ws = (char*)d_ws;
    unsigned short* edge_bf = (unsigned short*)(ws);            // 8,388,608
    float* traw     = (float*)(ws + 8388608);                   //   262,144
    float* robot_h  = (float*)(ws + 8650752);                   //   524,288
    float* target_h = (float*)(ws + 9175040);                   //   524,288
    unsigned short* WcT = (unsigned short*)(ws + 9699328);      //   393,216
    float* bc       = (float*)(ws + 10092544);                  //     6,144
    float* rWa      = (float*)(ws + 10098688);                  //   524,288
    float* tWa      = (float*)(ws + 10622976);                  //   524,288
    float* agg      = (float*)(ws + 11147264);                  //   524,288
    float* rS       = (float*)(ws + 11671552);                  //   524,288
    float* tST      = (float*)(ws + 12195840);                  //   524,288
    unsigned short* WTbig = (unsigned short*)(ws + 12720128);   // 3,145,728
    unsigned short* WT2   = (unsigned short*)(ws + 15865856);   // 1,835,008

    float* out    = (float*)d_out;
    float* probs  = out;            // output 0
    float* scores = out + 32768;    // output 1

    hipLaunchKernelGGL(k_prep, dim3(512), dim3(256), 0, stream, edge_raw, edge_bf, traw);
    hipLaunchKernelGGL(k_wc, dim3(774), dim3(256), 0, stream, Wp, bp, W_r2t, b_r2t, W_t2r, b_t2r, WcT, bc);
    hipLaunchKernelGGL(k_split, dim3(3328), dim3(256), 0, stream, W_pt, W_pr, W_t2r, W_r2t, Ws1, WTbig, WT2);
    hipLaunchKernelGGL(k_proj, dim3(512), dim3(256), 0, stream,
                       robot_raw, traw, Wp, bp, W_r2t, robot_h, target_h, rWa);

    for (int l = 0; l < 3; ++l) {
        // r2t bigpass + prefetch of the target-update weights
        {
            const unsigned short* pA = WTbig + (2 * l) * 262144;       // hi+lo, 512KB
            const unsigned short* pB = WT2 + (2 * l) * 131072;
            int bB = (l == 2) ? (3 * 262144) : 262144;                 // l==2: mats 4..6 (covers W2b too)
            hipLaunchKernelGGL(k_bigpass, dim3(512), dim3(256), 0, stream,
                               edge_bf, WcT + (2 * l) * 32768, bc + (2 * l) * 256, rWa, agg, 0,
                               pA, 524288, pB, bB);
        }
        const unsigned short* W2b = (l == 2) ? (WT2 + 6 * 131072) : nullptr;
        const float* b2b = (l == 2) ? bs1 : nullptr;
        float* o2b = (l == 2) ? tST : nullptr;
        hipLaunchKernelGGL(k_update_mfma, dim3(32), dim3(512), 0, stream,
                           target_h, agg, WTbig + (2 * l) * 262144,
                           b_pt + l * 256, g_t + l * 256, be_t + l * 256,
                           WT2 + (2 * l) * 131072, tWa, W2b, b2b, o2b);
        // t2r bigpass + prefetch of the robot-update weights
        {
            const unsigned short* pA = WTbig + (2 * l + 1) * 262144;
            int m2 = (l < 2) ? (2 * l + 1) : 5;
            const unsigned short* pB = WT2 + m2 * 131072;
            hipLaunchKernelGGL(k_bigpass, dim3(512), dim3(256), 0, stream,
                               edge_bf, WcT + (2 * l + 1) * 32768, bc + (2 * l + 1) * 256, tWa, agg, 1,
                               pA, 524288, pB, 262144);
        }
        const unsigned short* W2a = (l < 2) ? (WT2 + (2 * l + 1) * 131072) : (WT2 + 5 * 131072);
        float* o2a = (l < 2) ? rWa : rS;
        hipLaunchKernelGGL(k_update_mfma, dim3(32), dim3(512), 0, stream,
                           robot_h, agg, WTbig + (2 * l + 1) * 262144,
                           b_pr + l * 256, g_r + l * 256, be_r + l * 256,
                           W2a, o2a, (const unsigned short*)nullptr, (const float*)nullptr, (float*)nullptr);
    }

    hipLaunchKernelGGL(k_scores, dim3(128), dim3(256), 0, stream, rS, tST, Ws2, bs2, scores);
    hipLaunchKernelGGL(k_sinkhorn, dim3(8), dim3(256), 0, stream, scores, probs);
}

// Round 6
// 325.203 us; speedup vs baseline: 1.5817x; 1.1809x over previous
//
#include <hip/hip_runtime.h>

// NavAssignNet on MI355X — round 6.
//   - sinkhorn: 1024 thr/WG (4 waves/SIMD TLP), v[4]/thread, 1 barrier/iter
//   - bigpass: all 32 A/B fragment loads hoisted ahead of MFMA loop
//     (sched_barrier-fenced) -> one L2/HBM latency window instead of 4
//   - k_wc + k_split merged into k_weights (one dispatch)

typedef short bf16x8 __attribute__((ext_vector_type(8)));
typedef float f32x4 __attribute__((ext_vector_type(4)));

#define DEV static __device__ __forceinline__

DEV unsigned short f2bf(float x) {
    unsigned u = __float_as_uint(x);
    return (unsigned short)((u + 0x7fffu + ((u >> 16) & 1u)) >> 16);
}
DEV void split2(float v, unsigned short& hi, unsigned short& lo) {
    unsigned short h = f2bf(v);
    float fh = __uint_as_float(((unsigned)h) << 16);
    hi = h;
    lo = f2bf(v - fh);
}

// ---- 1. prep: edge_raw -> bf16 AND traw = mean over i, 512 WGs ----
__global__ __launch_bounds__(256) void k_prep(const float* __restrict__ edge,
                                              unsigned short* __restrict__ edge_bf,
                                              float* __restrict__ traw) {
    int wg = blockIdx.x;                 // 512 = b*64 + j
    int b = wg >> 6, j = wg & 63;
    int t = threadIdx.x;
    int d = t & 127, ih = t >> 7;        // ih: i-half
    float s = 0.f;
    long base = ((long)(b * 64 + ih * 32) * 64 + j) * 128 + d;
#pragma unroll 8
    for (int ii = 0; ii < 32; ++ii) {
        long idx = base + (long)ii * 8192;
        float v = edge[idx];
        s += v;
        edge_bf[idx] = f2bf(v);
    }
    __shared__ float part[128];
    if (ih == 1) part[d] = s;
    __syncthreads();
    if (ih == 0) traw[(b * 64 + j) * 128 + d] = (s + part[d]) * (1.f / 64.f);
}

// ---- 2. weights: WcT/bc (blk<774) + WT hi/lo split planes (blk>=774) ----
__global__ __launch_bounds__(256) void k_weights(const float* __restrict__ Wp,
                                                 const float* __restrict__ bp,
                                                 const float* __restrict__ W_r2t,
                                                 const float* __restrict__ b_r2t,
                                                 const float* __restrict__ W_t2r,
                                                 const float* __restrict__ b_t2r,
                                                 const float* __restrict__ W_pt,
                                                 const float* __restrict__ W_pr,
                                                 const float* __restrict__ Ws1,
                                                 unsigned short* __restrict__ WcT,
                                                 float* __restrict__ bc,
                                                 unsigned short* __restrict__ WTbig,
                                                 unsigned short* __restrict__ WT2) {
    int blk0 = blockIdx.x;
    int h = threadIdx.x;
    if (blk0 < 774) {
        int blk = blk0;
        if (blk < 768) {
            int p = blk >> 7, d = blk & 127, l = p >> 1;
            const float* Wb = ((p & 1) ? W_t2r : W_r2t) + l * 512 * 256 + 256 * 256;
            float acc = 0.f;
            for (int k = 0; k < 256; ++k) acc += Wp[d * 256 + k] * Wb[k * 256 + h];
            WcT[p * 32768 + h * 128 + d] = f2bf(acc);
        } else {
            int p = blk - 768, l = p >> 1;
            const float* Wb = ((p & 1) ? W_t2r : W_r2t) + l * 512 * 256 + 256 * 256;
            const float* bm = ((p & 1) ? b_t2r : b_r2t) + l * 256;
            float acc = bm[h];
            for (int k = 0; k < 256; ++k) acc += bp[k] * Wb[k * 256 + h];
            bc[p * 256 + h] = acc;
        }
        return;
    }
    int blk = blk0 - 774, t = threadIdx.x;
    if (blk < 1536) {
        int mat = blk >> 8, hh = blk & 255, l = mat >> 1;
        const float* W = ((mat & 1) ? W_pr : W_pt) + l * 512 * 256;
        unsigned short* dh = WTbig + mat * 262144 + hh * 512;
        unsigned short* dl = dh + 131072;
        for (int k = t; k < 512; k += 256) {
            unsigned short hi, lo;
            split2(W[k * 256 + hh], hi, lo);
            dh[k] = hi; dl[k] = lo;
        }
    } else {
        int m2 = blk - 1536, mat = m2 >> 8, hh = m2 & 255;
        const float* W;
        if (mat == 6) W = Ws1 + 256 * 256;
        else if (mat == 5) W = Ws1;
        else if (mat & 1) W = W_r2t + ((mat >> 1) + 1) * 512 * 256;
        else W = W_t2r + (mat >> 1) * 512 * 256;
        unsigned short* dh = WT2 + mat * 131072 + hh * 256;
        unsigned short* dl = dh + 65536;
        unsigned short hi, lo;
        split2(W[t * 256 + hh], hi, lo);
        dh[t] = hi; dl[t] = lo;
    }
}

// ---- 3. proj: robot_h/target_h = X @ Wp + bp ; robot WGs also emit rWa0 ----
__global__ __launch_bounds__(256) void k_proj(const float* __restrict__ robot_raw,
                                              const float* __restrict__ traw,
                                              const float* __restrict__ Wp,
                                              const float* __restrict__ bp,
                                              const float* __restrict__ Wa0,
                                              float* __restrict__ robot_h,
                                              float* __restrict__ target_h,
                                              float* __restrict__ rWa) {
    int h = threadIdx.x;
    int r0 = blockIdx.x * 2;
    int robot = (r0 < 512);
    const float* in;
    float* out;
    if (robot) { in = robot_raw + r0 * 128; out = robot_h + r0 * 256; }
    else       { in = traw + (r0 - 512) * 128; out = target_h + (r0 - 512) * 256; }
    float a0 = 0, a1 = 0;
    for (int k = 0; k < 128; ++k) {
        float w = Wp[k * 256 + h];
        a0 += in[k] * w; a1 += in[128 + k] * w;
    }
    float b = bp[h];
    a0 += b; a1 += b;
    out[h] = a0; out[256 + h] = a1;

    __shared__ float yl[2][257];
    if (robot) { yl[0][h] = a0; yl[1][h] = a1; }
    __syncthreads();
    if (robot) {
        float c0 = 0, c1 = 0;
        for (int k = 0; k < 256; ++k) {
            float w = Wa0[k * 256 + h];
            c0 += yl[0][k] * w; c1 += yl[1][k] * w;
        }
        rWa[r0 * 256 + h] = c0; rWa[(r0 + 1) * 256 + h] = c1;
    }
}

// ---- 4. update via MFMA split-bf16, 512 threads / 8 waves (32 cols each) ----
__global__ __launch_bounds__(512) void k_update_mfma(
        float* __restrict__ state, const float* __restrict__ agg,
        const unsigned short* __restrict__ WTm,   // [hi 256x512][lo 256x512]
        const float* __restrict__ bvec, const float* __restrict__ g, const float* __restrict__ be,
        const unsigned short* __restrict__ WT2a,  // [hi 256x256][lo 256x256]
        float* __restrict__ out2a,
        const unsigned short* __restrict__ WT2b, const float* __restrict__ b2b,
        float* __restrict__ out2b) {
    int r0 = blockIdx.x * 16;
    int t = threadIdx.x;
    int w = t >> 6, lane = t & 63;
    int c16 = lane & 15, kg = lane >> 4;
    int colbase = 32 * w + c16;

    __shared__ unsigned short Ahi[16 * 512];
    __shared__ unsigned short Alo[16 * 512];
    __shared__ unsigned short Yhi[16 * 256];
    __shared__ unsigned short Ylo[16 * 256];
    __shared__ float red[8][16][2];

    // stage A = [state | agg] rows r0..r0+15 as swizzled hi/lo bf16
    {
        int row = t & 15, kq = t >> 4;   // kq 0..31 -> 16 K-elems each
        const float* src = (kq < 16) ? (state + (r0 + row) * 256 + kq * 16)
                                     : (agg + (r0 + row) * 256 + (kq - 16) * 16);
#pragma unroll
        for (int blk = 0; blk < 2; ++blk) {
            float4 a = *(const float4*)(src + blk * 8);
            float4 b2 = *(const float4*)(src + blk * 8 + 4);
            unsigned short h[8], lo[8];
            split2(a.x, h[0], lo[0]); split2(a.y, h[1], lo[1]);
            split2(a.z, h[2], lo[2]); split2(a.w, h[3], lo[3]);
            split2(b2.x, h[4], lo[4]); split2(b2.y, h[5], lo[5]);
            split2(b2.z, h[6], lo[6]); split2(b2.w, h[7], lo[7]);
            int byte = row * 1024 + (kq * 16 + blk * 8) * 2;
            byte ^= (row & 7) << 4;
            ushort4* ph = (ushort4*)((char*)Ahi + byte);
            ph[0] = make_ushort4(h[0], h[1], h[2], h[3]);
            ph[1] = make_ushort4(h[4], h[5], h[6], h[7]);
            ushort4* pl = (ushort4*)((char*)Alo + byte);
            pl[0] = make_ushort4(lo[0], lo[1], lo[2], lo[3]);
            pl[1] = make_ushort4(lo[4], lo[5], lo[6], lo[7]);
        }
    }
    __syncthreads();

    // main GEMM: K=512, 3-term split, 2 col-tiles per wave
    f32x4 acc[2];
#pragma unroll
    for (int ni = 0; ni < 2; ++ni) acc[ni] = f32x4{0.f, 0.f, 0.f, 0.f};
    const unsigned short* Bh0 = WTm + colbase * 512 + kg * 8;
#pragma unroll 2
    for (int ks = 0; ks < 16; ++ks) {
        int ab = c16 * 1024 + ks * 64 + kg * 16;
        ab ^= (c16 & 7) << 4;
        bf16x8 ah = *(const bf16x8*)((const char*)Ahi + ab);
        bf16x8 al = *(const bf16x8*)((const char*)Alo + ab);
#pragma unroll
        for (int ni = 0; ni < 2; ++ni) {
            const unsigned short* p = Bh0 + ni * 16 * 512 + ks * 32;
            bf16x8 bh = *(const bf16x8*)p;
            bf16x8 bl = *(const bf16x8*)(p + 131072);
            acc[ni] = __builtin_amdgcn_mfma_f32_16x16x32_bf16(ah, bh, acc[ni], 0, 0, 0);
            acc[ni] = __builtin_amdgcn_mfma_f32_16x16x32_bf16(al, bh, acc[ni], 0, 0, 0);
            acc[ni] = __builtin_amdgcn_mfma_f32_16x16x32_bf16(ah, bl, acc[ni], 0, 0, 0);
        }
    }

    // residual + bias
    float x[2][4];
#pragma unroll
    for (int ni = 0; ni < 2; ++ni) {
        int col = colbase + 16 * ni;
        float bv = bvec[col];
#pragma unroll
        for (int r = 0; r < 4; ++r) {
            int row = kg * 4 + r;
            x[ni][r] = acc[ni][r] + state[(r0 + row) * 256 + col] + bv;
        }
    }

    // LN stats
    float s[4], q[4];
#pragma unroll
    for (int r = 0; r < 4; ++r) {
        s[r] = x[0][r] + x[1][r];
        q[r] = x[0][r] * x[0][r] + x[1][r] * x[1][r];
#pragma unroll
        for (int m = 1; m < 16; m <<= 1) {
            s[r] += __shfl_xor(s[r], m);
            q[r] += __shfl_xor(q[r], m);
        }
    }
    if (c16 == 0) {
#pragma unroll
        for (int r = 0; r < 4; ++r) {
            red[w][kg * 4 + r][0] = s[r];
            red[w][kg * 4 + r][1] = q[r];
        }
    }
    __syncthreads();
    float mr[4], rsr[4];
#pragma unroll
    for (int r = 0; r < 4; ++r) {
        int row = kg * 4 + r;
        float S = 0.f, Q = 0.f;
#pragma unroll
        for (int w2 = 0; w2 < 8; ++w2) { S += red[w2][row][0]; Q += red[w2][row][1]; }
        float m = S * (1.f / 256.f);
        float v = Q * (1.f / 256.f) - m * m;
        mr[r] = m;
        rsr[r] = rsqrtf(v + 1e-5f);
    }

    // y = LN(x): store to state + stage bf16 hi/lo into LDS (swizzled)
#pragma unroll
    for (int ni = 0; ni < 2; ++ni) {
        int col = colbase + 16 * ni;
        float gg = g[col], bb = be[col];
#pragma unroll
        for (int r = 0; r < 4; ++r) {
            int row = kg * 4 + r;
            float y = (x[ni][r] - mr[r]) * rsr[r] * gg + bb;
            state[(r0 + row) * 256 + col] = y;
            unsigned short yh, yl2;
            split2(y, yh, yl2);
            int byte = (row * 512 + col * 2) ^ ((row & 7) << 4);
            *(unsigned short*)((char*)Yhi + byte) = yh;
            *(unsigned short*)((char*)Ylo + byte) = yl2;
        }
    }
    __syncthreads();

    // fused GEMM(s): y @ W2a (-> out2a), optional y @ W2b + b2b (-> out2b transposed)
    f32x4 acc2[2], acc3[2];
#pragma unroll
    for (int ni = 0; ni < 2; ++ni) { acc2[ni] = f32x4{0.f, 0.f, 0.f, 0.f}; acc3[ni] = f32x4{0.f, 0.f, 0.f, 0.f}; }
    const unsigned short* B2h0 = WT2a + colbase * 256 + kg * 8;
    const unsigned short* B3h0 = WT2b ? (WT2b + colbase * 256 + kg * 8) : B2h0;
    int haveB = (WT2b != nullptr);
#pragma unroll 2
    for (int ks = 0; ks < 8; ++ks) {
        int ab = c16 * 512 + ks * 64 + kg * 16;
        ab ^= (c16 & 7) << 4;
        bf16x8 ah = *(const bf16x8*)((const char*)Yhi + ab);
        bf16x8 al = *(const bf16x8*)((const char*)Ylo + ab);
#pragma unroll
        for (int ni = 0; ni < 2; ++ni) {
            const unsigned short* p = B2h0 + ni * 16 * 256 + ks * 32;
            bf16x8 bh = *(const bf16x8*)p;
            bf16x8 bl = *(const bf16x8*)(p + 65536);
            acc2[ni] = __builtin_amdgcn_mfma_f32_16x16x32_bf16(ah, bh, acc2[ni], 0, 0, 0);
            acc2[ni] = __builtin_amdgcn_mfma_f32_16x16x32_bf16(al, bh, acc2[ni], 0, 0, 0);
            acc2[ni] = __builtin_amdgcn_mfma_f32_16x16x32_bf16(ah, bl, acc2[ni], 0, 0, 0);
            if (haveB) {
                const unsigned short* p3 = B3h0 + ni * 16 * 256 + ks * 32;
                bf16x8 bh3 = *(const bf16x8*)p3;
                bf16x8 bl3 = *(const bf16x8*)(p3 + 65536);
                acc3[ni] = __builtin_amdgcn_mfma_f32_16x16x32_bf16(ah, bh3, acc3[ni], 0, 0, 0);
                acc3[ni] = __builtin_amdgcn_mfma_f32_16x16x32_bf16(al, bh3, acc3[ni], 0, 0, 0);
                acc3[ni] = __builtin_amdgcn_mfma_f32_16x16x32_bf16(ah, bl3, acc3[ni], 0, 0, 0);
            }
        }
    }
#pragma unroll
    for (int ni = 0; ni < 2; ++ni) {
        int col = colbase + 16 * ni;
#pragma unroll
        for (int r = 0; r < 4; ++r) {
            int row = kg * 4 + r;
            out2a[(r0 + row) * 256 + col] = acc2[ni][r];
        }
    }
    if (haveB) {
#pragma unroll
        for (int ni = 0; ni < 2; ++ni) {
            int col = colbase + 16 * ni;
            float bb2 = b2b[col];
#pragma unroll
            for (int r = 0; r < 4; ++r) {
                int grow = r0 + kg * 4 + r;
                int b0 = grow >> 6, j = grow & 63;
                out2b[(b0 * 256 + col) * 64 + j] = acc3[ni][r] + bb2;
            }
        }
    }
}

// ---- 5. bigpass: hoisted loads + distributed L2 prefetch ----
__global__ __launch_bounds__(256) void k_bigpass(const unsigned short* __restrict__ edge_bf,
                                                 const unsigned short* __restrict__ WcT,
                                                 const float* __restrict__ bc,
                                                 const float* __restrict__ rowbias,
                                                 float* __restrict__ agg,
                                                 int mode,
                                                 const unsigned short* __restrict__ prefA,
                                                 int bytesA,
                                                 const unsigned short* __restrict__ prefB,
                                                 int bytesB) {
    int wg = blockIdx.x;                 // 512 = b*64 + jj
    int b = wg >> 6, jj = wg & 63;
    int w = threadIdx.x >> 6, lane = threadIdx.x & 63;
    int row16 = lane & 15, kgrp = lane >> 4;

    int rstride = (mode == 0) ? 8192 : 128;
    const unsigned short* Ap = edge_bf + b * 524288 + ((mode == 0) ? jj * 128 : jj * 8192)
                             + row16 * rstride + 8 * kgrp;
    const unsigned short* Bp = WcT + (64 * w + row16) * 128 + 8 * kgrp;

    // hoist ALL fragment loads: one latency window instead of four
    bf16x8 av[4][4], bv[4][4];
#pragma unroll
    for (int kk = 0; kk < 4; ++kk) {
#pragma unroll
        for (int mi = 0; mi < 4; ++mi)
            av[mi][kk] = *(const bf16x8*)(Ap + mi * 16 * rstride + kk * 32);
#pragma unroll
        for (int ni = 0; ni < 4; ++ni)
            bv[ni][kk] = *(const bf16x8*)(Bp + ni * 2048 + kk * 32);
    }
    __builtin_amdgcn_sched_barrier(0);

    f32x4 acc[4][4];
#pragma unroll
    for (int mi = 0; mi < 4; ++mi)
#pragma unroll
        for (int ni = 0; ni < 4; ++ni) acc[mi][ni] = f32x4{0.f, 0.f, 0.f, 0.f};
#pragma unroll
    for (int kk = 0; kk < 4; ++kk)
#pragma unroll
        for (int mi = 0; mi < 4; ++mi)
#pragma unroll
            for (int ni = 0; ni < 4; ++ni)
                acc[mi][ni] = __builtin_amdgcn_mfma_f32_16x16x32_bf16(av[mi][kk], bv[ni][kk], acc[mi][ni], 0, 0, 0);

    const float* rb = rowbias + (b * 64) * 256;
    float colsum[4] = {0.f, 0.f, 0.f, 0.f};
#pragma unroll
    for (int ni = 0; ni < 4; ++ni) {
        int col = 64 * w + 16 * ni + row16;
        float bch = bc[col];
#pragma unroll
        for (int mi = 0; mi < 4; ++mi) {
            int rbase = 16 * mi + 4 * kgrp;
#pragma unroll
            for (int r = 0; r < 4; ++r) {
                float v = acc[mi][ni][r] + rb[(rbase + r) * 256 + col] + bch;
                colsum[ni] += fmaxf(v, 0.f);
            }
        }
    }
#pragma unroll
    for (int ni = 0; ni < 4; ++ni) {
        colsum[ni] += __shfl_xor(colsum[ni], 16);
        colsum[ni] += __shfl_xor(colsum[ni], 32);
    }
    if (kgrp == 0) {
        float* o = agg + (b * 64 + jj) * 256 + 64 * w + row16;
#pragma unroll
        for (int ni = 0; ni < 4; ++ni) o[16 * ni] = colsum[ni] * (1.f / 64.f);
    }

    // tail prefetch: this WG's 1/64 slice of the next update's weight panels
    unsigned accp = 0;
    int s = (blockIdx.x >> 3) & 63;
    {
        int na = bytesA >> 10;           // uint4 per slice (= bytes/64/16)
        const uint4* pa = (const uint4*)prefA + (long)s * na;
        for (int i = threadIdx.x; i < na; i += 256) {
            uint4 v = pa[i];
            accp ^= v.x ^ v.y ^ v.z ^ v.w;
        }
        int nb = bytesB >> 10;
        const uint4* pb = (const uint4*)prefB + (long)s * nb;
        for (int i = threadIdx.x; i < nb; i += 256) {
            uint4 v = pb[i];
            accp ^= v.x ^ v.y ^ v.z ^ v.w;
        }
    }
    asm volatile("" :: "v"(accp));
}

// ---- 6. scores ----
__global__ __launch_bounds__(256) void k_scores(const float* __restrict__ rS,
                                                const float* __restrict__ tST,
                                                const float* __restrict__ Ws2,
                                                const float* __restrict__ bs2,
                                                float* __restrict__ scores) {
    int t = blockIdx.x * 256 + threadIdx.x;          // 32768
    int j = t & 63, i = (t >> 6) & 63, b = t >> 12;
    const float* rs = rS + (b * 64 + i) * 256;
    const float* ts = tST + b * 256 * 64 + j;
    float acc = bs2[0];
    for (int h = 0; h < 256; ++h)
        acc += fmaxf(rs[h] + ts[h * 64], 0.f) * Ws2[h];
    scores[t] = acc;
}

// ---- 7. sinkhorn: 1024 threads, v[4]/thread, double-buffered partials ----
__global__ __launch_bounds__(1024) void k_sinkhorn(const float* __restrict__ scores,
                                                   float* __restrict__ probs) {
    int b = blockIdx.x;
    int t = threadIdx.x;
    int j = t & 63, rg = t >> 6;         // 16 row-groups x 4 rows
    float v[4];
    const float* src = scores + b * 4096 + rg * 256 + j;
#pragma unroll
    for (int k = 0; k < 4; ++k) v[k] = src[k * 64];

    __shared__ float lm_s[2][16][64];
    __shared__ float ps_s[2][16][64];

    for (int it = 0; it < 10; ++it) {
        // row LSE (over j = lane): 4 independent wave butterflies
#pragma unroll
        for (int k = 0; k < 4; ++k) {
            float m = v[k];
#pragma unroll
            for (int s = 1; s < 64; s <<= 1) m = fmaxf(m, __shfl_xor(m, s));
            float e = __expf(v[k] - m), ss = e;
#pragma unroll
            for (int s = 1; s < 64; s <<= 1) ss += __shfl_xor(ss, s);
            v[k] -= m + __logf(ss);
        }
        // col LSE (over i): local 4 + LDS combine of 16 row-group partials
        int p = it & 1;
        float lm = fmaxf(fmaxf(v[0], v[1]), fmaxf(v[2], v[3]));
        float ps = __expf(v[0] - lm) + __expf(v[1] - lm) + __expf(v[2] - lm) + __expf(v[3] - lm);
        lm_s[p][rg][j] = lm; ps_s[p][rg][j] = ps;
        __syncthreads();
        float M = lm_s[p][0][j];
#pragma unroll
        for (int g2 = 1; g2 < 16; ++g2) M = fmaxf(M, lm_s[p][g2][j]);
        float S = 0.f;
#pragma unroll
        for (int g2 = 0; g2 < 16; ++g2) S += ps_s[p][g2][j] * __expf(lm_s[p][g2][j] - M);
        float lse = M + __logf(S);
#pragma unroll
        for (int k = 0; k < 4; ++k) v[k] -= lse;
    }
    float* dst = probs + b * 4096 + rg * 256 + j;
#pragma unroll
    for (int k = 0; k < 4; ++k) dst[k * 64] = __expf(v[k]);
}

extern "C" void kernel_launch(void* const* d_in, const int* in_sizes, int n_in,
                              void* d_out, int out_size, void* d_ws, size_t ws_size,
                              hipStream_t stream) {
    const float* robot_raw = (const float*)d_in[0];
    const float* edge_raw  = (const float*)d_in[1];
    const float* Wp    = (const float*)d_in[2];
    const float* bp    = (const float*)d_in[3];
    const float* W_r2t = (const float*)d_in[4];
    const float* b_r2t = (const float*)d_in[5];
    const float* W_pt  = (const float*)d_in[6];
    const float* b_pt  = (const float*)d_in[7];
    const float* g_t   = (const float*)d_in[8];
    const float* be_t  = (const float*)d_in[9];
    const float* W_t2r = (const float*)d_in[10];
    const float* b_t2r = (const float*)d_in[11];
    const float* W_pr  = (const float*)d_in[12];
    const float* b_pr  = (const float*)d_in[13];
    const float* g_r   = (const float*)d_in[14];
    const float* be_r  = (const float*)d_in[15];
    const float* Ws1   = (const float*)d_in[16];
    const float* bs1   = (const float*)d_in[17];
    const float* Ws2   = (const float*)d_in[18];
    const float* bs2   = (const float*)d_in[19];

    char* ws = (char*)d_ws;
    unsigned short* edge_bf = (unsigned short*)(ws);            // 8,388,608
    float* traw     = (float*)(ws + 8388608);                   //   262,144
    float* robot_h  = (float*)(ws + 8650752);                   //   524,288
    float* target_h = (float*)(ws + 9175040);                   //   524,288
    unsigned short* WcT = (unsigned short*)(ws + 9699328);      //   393,216
    float* bc       = (float*)(ws + 10092544);                  //     6,144
    float* rWa      = (float*)(ws + 10098688);                  //   524,288
    float* tWa      = (float*)(ws + 10622976);                  //   524,288
    float* agg      = (float*)(ws + 11147264);                  //   524,288
    float* rS       = (float*)(ws + 11671552);                  //   524,288
    float* tST      = (float*)(ws + 12195840);                  //   524,288
    unsigned short* WTbig = (unsigned short*)(ws + 12720128);   // 3,145,728
    unsigned short* WT2   = (unsigned short*)(ws + 15865856);   // 1,835,008

    float* out    = (float*)d_out;
    float* probs  = out;            // output 0
    float* scores = out + 32768;    // output 1

    hipLaunchKernelGGL(k_prep, dim3(512), dim3(256), 0, stream, edge_raw, edge_bf, traw);
    hipLaunchKernelGGL(k_weights, dim3(4102), dim3(256), 0, stream,
                       Wp, bp, W_r2t, b_r2t, W_t2r, b_t2r, W_pt, W_pr, Ws1, WcT, bc, WTbig, WT2);
    hipLaunchKernelGGL(k_proj, dim3(512), dim3(256), 0, stream,
                       robot_raw, traw, Wp, bp, W_r2t, robot_h, target_h, rWa);

    for (int l = 0; l < 3; ++l) {
        // r2t bigpass + prefetch of the target-update weights
        {
            const unsigned short* pA = WTbig + (2 * l) * 262144;       // hi+lo, 512KB
            const unsigned short* pB = WT2 + (2 * l) * 131072;
            int bB = (l == 2) ? (3 * 262144) : 262144;                 // l==2: mats 4..6 (covers W2b too)
            hipLaunchKernelGGL(k_bigpass, dim3(512), dim3(256), 0, stream,
                               edge_bf, WcT + (2 * l) * 32768, bc + (2 * l) * 256, rWa, agg, 0,
                               pA, 524288, pB, bB);
        }
        const unsigned short* W2b = (l == 2) ? (WT2 + 6 * 131072) : nullptr;
        const float* b2b = (l == 2) ? bs1 : nullptr;
        float* o2b = (l == 2) ? tST : nullptr;
        hipLaunchKernelGGL(k_update_mfma, dim3(32), dim3(512), 0, stream,
                           target_h, agg, WTbig + (2 * l) * 262144,
                           b_pt + l * 256, g_t + l * 256, be_t + l * 256,
                           WT2 + (2 * l) * 131072, tWa, W2b, b2b, o2b);
        // t2r bigpass + prefetch of the robot-update weights
        {
            const unsigned short* pA = WTbig + (2 * l + 1) * 262144;
            int m2 = (l < 2) ? (2 * l + 1) : 5;
            const unsigned short* pB = WT2 + m2 * 131072;
            hipLaunchKernelGGL(k_bigpass, dim3(512), dim3(256), 0, stream,
                               edge_bf, WcT + (2 * l + 1) * 32768, bc + (2 * l + 1) * 256, tWa, agg, 1,
                               pA, 524288, pB, 262144);
        }
        const unsigned short* W2a = (l < 2) ? (WT2 + (2 * l + 1) * 131072) : (WT2 + 5 * 131072);
        float* o2a = (l < 2) ? rWa : rS;
        hipLaunchKernelGGL(k_update_mfma, dim3(32), dim3(512), 0, stream,
                           robot_h, agg, WTbig + (2 * l + 1) * 262144,
                           b_pr + l * 256, g_r + l * 256, be_r + l * 256,
                           W2a, o2a, (const unsigned short*)nullptr, (const float*)nullptr, (float*)nullptr);
    }

    hipLaunchKernelGGL(k_scores, dim3(128), dim3(256), 0, stream, rS, tST, Ws2, bs2, scores);
    hipLaunchKernelGGL(k_sinkhorn, dim3(8), dim3(1024), 0, stream, scores, probs);
}

// Round 7
// 321.149 us; speedup vs baseline: 1.6017x; 1.0126x over previous
//
#include <hip/hip_runtime.h>

// NavAssignNet on MI355X — round 7.
//   - k_update_mfma: 1024 thr / 16 waves, 16 cols per wave (2x waves/SIMD,
//     half the L2 loads per wave -> latency-hiding on the 32-CU update)
//   - k_bigpass: prefetch loads issued between MFMA and epilogue (overlap
//     HBM latency with epilogue), consumed at kernel end
//   - k_prep + k_weights merged into one dispatch

typedef short bf16x8 __attribute__((ext_vector_type(8)));
typedef float f32x4 __attribute__((ext_vector_type(4)));

#define DEV static __device__ __forceinline__

DEV unsigned short f2bf(float x) {
    unsigned u = __float_as_uint(x);
    return (unsigned short)((u + 0x7fffu + ((u >> 16) & 1u)) >> 16);
}
DEV void split2(float v, unsigned short& hi, unsigned short& lo) {
    unsigned short h = f2bf(v);
    float fh = __uint_as_float(((unsigned)h) << 16);
    hi = h;
    lo = f2bf(v - fh);
}

// ---- 1. prep+weights merged ----
// blk < 512: edge_raw -> bf16 + traw mean.  blk >= 512: WcT/bc + WT splits.
__global__ __launch_bounds__(256) void k_prep_w(const float* __restrict__ edge,
                                                unsigned short* __restrict__ edge_bf,
                                                float* __restrict__ traw,
                                                const float* __restrict__ Wp,
                                                const float* __restrict__ bp,
                                                const float* __restrict__ W_r2t,
                                                const float* __restrict__ b_r2t,
                                                const float* __restrict__ W_t2r,
                                                const float* __restrict__ b_t2r,
                                                const float* __restrict__ W_pt,
                                                const float* __restrict__ W_pr,
                                                const float* __restrict__ Ws1,
                                                unsigned short* __restrict__ WcT,
                                                float* __restrict__ bc,
                                                unsigned short* __restrict__ WTbig,
                                                unsigned short* __restrict__ WT2) {
    if (blockIdx.x < 512) {
        int wg = blockIdx.x;             // b*64 + j
        int b = wg >> 6, j = wg & 63;
        int t = threadIdx.x;
        int d = t & 127, ih = t >> 7;
        float s = 0.f;
        long base = ((long)(b * 64 + ih * 32) * 64 + j) * 128 + d;
#pragma unroll 8
        for (int ii = 0; ii < 32; ++ii) {
            long idx = base + (long)ii * 8192;
            float v = edge[idx];
            s += v;
            edge_bf[idx] = f2bf(v);
        }
        __shared__ float part[128];
        if (ih == 1) part[d] = s;
        __syncthreads();
        if (ih == 0) traw[(b * 64 + j) * 128 + d] = (s + part[d]) * (1.f / 64.f);
        return;
    }
    int blk0 = blockIdx.x - 512;
    int h = threadIdx.x;
    if (blk0 < 774) {
        int blk = blk0;
        if (blk < 768) {
            int p = blk >> 7, d = blk & 127, l = p >> 1;
            const float* Wb = ((p & 1) ? W_t2r : W_r2t) + l * 512 * 256 + 256 * 256;
            float acc = 0.f;
            for (int k = 0; k < 256; ++k) acc += Wp[d * 256 + k] * Wb[k * 256 + h];
            WcT[p * 32768 + h * 128 + d] = f2bf(acc);
        } else {
            int p = blk - 768, l = p >> 1;
            const float* Wb = ((p & 1) ? W_t2r : W_r2t) + l * 512 * 256 + 256 * 256;
            const float* bm = ((p & 1) ? b_t2r : b_r2t) + l * 256;
            float acc = bm[h];
            for (int k = 0; k < 256; ++k) acc += bp[k] * Wb[k * 256 + h];
            bc[p * 256 + h] = acc;
        }
        return;
    }
    int blk = blk0 - 774, t = threadIdx.x;
    if (blk < 1536) {
        int mat = blk >> 8, hh = blk & 255, l = mat >> 1;
        const float* W = ((mat & 1) ? W_pr : W_pt) + l * 512 * 256;
        unsigned short* dh = WTbig + mat * 262144 + hh * 512;
        unsigned short* dl = dh + 131072;
        for (int k = t; k < 512; k += 256) {
            unsigned short hi, lo;
            split2(W[k * 256 + hh], hi, lo);
            dh[k] = hi; dl[k] = lo;
        }
    } else {
        int m2 = blk - 1536, mat = m2 >> 8, hh = m2 & 255;
        const float* W;
        if (mat == 6) W = Ws1 + 256 * 256;
        else if (mat == 5) W = Ws1;
        else if (mat & 1) W = W_r2t + ((mat >> 1) + 1) * 512 * 256;
        else W = W_t2r + (mat >> 1) * 512 * 256;
        unsigned short* dh = WT2 + mat * 131072 + hh * 256;
        unsigned short* dl = dh + 65536;
        unsigned short hi, lo;
        split2(W[t * 256 + hh], hi, lo);
        dh[t] = hi; dl[t] = lo;
    }
}

// ---- 2. proj: robot_h/target_h = X @ Wp + bp ; robot WGs also emit rWa0 ----
__global__ __launch_bounds__(256) void k_proj(const float* __restrict__ robot_raw,
                                              const float* __restrict__ traw,
                                              const float* __restrict__ Wp,
                                              const float* __restrict__ bp,
                                              const float* __restrict__ Wa0,
                                              float* __restrict__ robot_h,
                                              float* __restrict__ target_h,
                                              float* __restrict__ rWa) {
    int h = threadIdx.x;
    int r0 = blockIdx.x * 2;
    int robot = (r0 < 512);
    const float* in;
    float* out;
    if (robot) { in = robot_raw + r0 * 128; out = robot_h + r0 * 256; }
    else       { in = traw + (r0 - 512) * 128; out = target_h + (r0 - 512) * 256; }
    float a0 = 0, a1 = 0;
    for (int k = 0; k < 128; ++k) {
        float w = Wp[k * 256 + h];
        a0 += in[k] * w; a1 += in[128 + k] * w;
    }
    float b = bp[h];
    a0 += b; a1 += b;
    out[h] = a0; out[256 + h] = a1;

    __shared__ float yl[2][257];
    if (robot) { yl[0][h] = a0; yl[1][h] = a1; }
    __syncthreads();
    if (robot) {
        float c0 = 0, c1 = 0;
        for (int k = 0; k < 256; ++k) {
            float w = Wa0[k * 256 + h];
            c0 += yl[0][k] * w; c1 += yl[1][k] * w;
        }
        rWa[r0 * 256 + h] = c0; rWa[(r0 + 1) * 256 + h] = c1;
    }
}

// ---- 3. update via MFMA split-bf16, 1024 threads / 16 waves (16 cols each) ----
__global__ __launch_bounds__(1024) void k_update_mfma(
        float* __restrict__ state, const float* __restrict__ agg,
        const unsigned short* __restrict__ WTm,   // [hi 256x512][lo 256x512]
        const float* __restrict__ bvec, const float* __restrict__ g, const float* __restrict__ be,
        const unsigned short* __restrict__ WT2a,  // [hi 256x256][lo 256x256]
        float* __restrict__ out2a,
        const unsigned short* __restrict__ WT2b, const float* __restrict__ b2b,
        float* __restrict__ out2b) {
    int r0 = blockIdx.x * 16;
    int t = threadIdx.x;
    int w = t >> 6, lane = t & 63;
    int c16 = lane & 15, kg = lane >> 4;
    int col = (w << 4) | c16;

    __shared__ unsigned short Ahi[16 * 512];
    __shared__ unsigned short Alo[16 * 512];
    __shared__ unsigned short Yhi[16 * 256];
    __shared__ unsigned short Ylo[16 * 256];
    __shared__ float red[16][16][2];

    // stage A = [state | agg] rows r0..r0+15 as swizzled hi/lo bf16 (8 elems/thread)
    {
        int row = t & 15, kq = t >> 4;   // kq 0..63 -> 8 K-elems each
        const float* src = (kq < 32) ? (state + (r0 + row) * 256 + kq * 8)
                                     : (agg + (r0 + row) * 256 + (kq - 32) * 8);
        float4 a = *(const float4*)(src);
        float4 b2 = *(const float4*)(src + 4);
        unsigned short h[8], lo[8];
        split2(a.x, h[0], lo[0]); split2(a.y, h[1], lo[1]);
        split2(a.z, h[2], lo[2]); split2(a.w, h[3], lo[3]);
        split2(b2.x, h[4], lo[4]); split2(b2.y, h[5], lo[5]);
        split2(b2.z, h[6], lo[6]); split2(b2.w, h[7], lo[7]);
        int byte = row * 1024 + kq * 16;
        byte ^= (row & 7) << 4;
        ushort4* ph = (ushort4*)((char*)Ahi + byte);
        ph[0] = make_ushort4(h[0], h[1], h[2], h[3]);
        ph[1] = make_ushort4(h[4], h[5], h[6], h[7]);
        ushort4* pl = (ushort4*)((char*)Alo + byte);
        pl[0] = make_ushort4(lo[0], lo[1], lo[2], lo[3]);
        pl[1] = make_ushort4(lo[4], lo[5], lo[6], lo[7]);
    }
    __syncthreads();

    // main GEMM: K=512, 3-term split, 1 col-tile per wave
    f32x4 acc = f32x4{0.f, 0.f, 0.f, 0.f};
    const unsigned short* Bh0 = WTm + col * 512 + kg * 8;
#pragma unroll 4
    for (int ks = 0; ks < 16; ++ks) {
        int ab = c16 * 1024 + ks * 64 + kg * 16;
        ab ^= (c16 & 7) << 4;
        bf16x8 ah = *(const bf16x8*)((const char*)Ahi + ab);
        bf16x8 al = *(const bf16x8*)((const char*)Alo + ab);
        const unsigned short* p = Bh0 + ks * 32;
        bf16x8 bh = *(const bf16x8*)p;
        bf16x8 bl = *(const bf16x8*)(p + 131072);
        acc = __builtin_amdgcn_mfma_f32_16x16x32_bf16(ah, bh, acc, 0, 0, 0);
        acc = __builtin_amdgcn_mfma_f32_16x16x32_bf16(al, bh, acc, 0, 0, 0);
        acc = __builtin_amdgcn_mfma_f32_16x16x32_bf16(ah, bl, acc, 0, 0, 0);
    }

    // residual + bias
    float x[4];
    {
        float bv = bvec[col];
#pragma unroll
        for (int r = 0; r < 4; ++r) {
            int row = kg * 4 + r;
            x[r] = acc[r] + state[(r0 + row) * 256 + col] + bv;
        }
    }

    // LN stats: reduce over 16 cols in-wave, then 16 waves via LDS
    float s[4], q[4];
#pragma unroll
    for (int r = 0; r < 4; ++r) {
        s[r] = x[r];
        q[r] = x[r] * x[r];
#pragma unroll
        for (int m = 1; m < 16; m <<= 1) {
            s[r] += __shfl_xor(s[r], m);
            q[r] += __shfl_xor(q[r], m);
        }
    }
    if (c16 == 0) {
#pragma unroll
        for (int r = 0; r < 4; ++r) {
            red[w][kg * 4 + r][0] = s[r];
            red[w][kg * 4 + r][1] = q[r];
        }
    }
    __syncthreads();
    float mr[4], rsr[4];
#pragma unroll
    for (int r = 0; r < 4; ++r) {
        int row = kg * 4 + r;
        float S = 0.f, Q = 0.f;
#pragma unroll
        for (int w2 = 0; w2 < 16; ++w2) { S += red[w2][row][0]; Q += red[w2][row][1]; }
        float m = S * (1.f / 256.f);
        float v = Q * (1.f / 256.f) - m * m;
        mr[r] = m;
        rsr[r] = rsqrtf(v + 1e-5f);
    }

    // y = LN(x): store to state + stage bf16 hi/lo into LDS (swizzled)
    {
        float gg = g[col], bb = be[col];
#pragma unroll
        for (int r = 0; r < 4; ++r) {
            int row = kg * 4 + r;
            float y = (x[r] - mr[r]) * rsr[r] * gg + bb;
            state[(r0 + row) * 256 + col] = y;
            unsigned short yh, yl2;
            split2(y, yh, yl2);
            int byte = (row * 512 + col * 2) ^ ((row & 7) << 4);
            *(unsigned short*)((char*)Yhi + byte) = yh;
            *(unsigned short*)((char*)Ylo + byte) = yl2;
        }
    }
    __syncthreads();

    // fused GEMM(s): y @ W2a (-> out2a), optional y @ W2b + b2b (-> out2b transposed)
    f32x4 acc2 = f32x4{0.f, 0.f, 0.f, 0.f};
    f32x4 acc3 = f32x4{0.f, 0.f, 0.f, 0.f};
    const unsigned short* B2h0 = WT2a + col * 256 + kg * 8;
    const unsigned short* B3h0 = WT2b ? (WT2b + col * 256 + kg * 8) : B2h0;
    int haveB = (WT2b != nullptr);
#pragma unroll 4
    for (int ks = 0; ks < 8; ++ks) {
        int ab = c16 * 512 + ks * 64 + kg * 16;
        ab ^= (c16 & 7) << 4;
        bf16x8 ah = *(const bf16x8*)((const char*)Yhi + ab);
        bf16x8 al = *(const bf16x8*)((const char*)Ylo + ab);
        const unsigned short* p = B2h0 + ks * 32;
        bf16x8 bh = *(const bf16x8*)p;
        bf16x8 bl = *(const bf16x8*)(p + 65536);
        acc2 = __builtin_amdgcn_mfma_f32_16x16x32_bf16(ah, bh, acc2, 0, 0, 0);
        acc2 = __builtin_amdgcn_mfma_f32_16x16x32_bf16(al, bh, acc2, 0, 0, 0);
        acc2 = __builtin_amdgcn_mfma_f32_16x16x32_bf16(ah, bl, acc2, 0, 0, 0);
        if (haveB) {
            const unsigned short* p3 = B3h0 + ks * 32;
            bf16x8 bh3 = *(const bf16x8*)p3;
            bf16x8 bl3 = *(const bf16x8*)(p3 + 65536);
            acc3 = __builtin_amdgcn_mfma_f32_16x16x32_bf16(ah, bh3, acc3, 0, 0, 0);
            acc3 = __builtin_amdgcn_mfma_f32_16x16x32_bf16(al, bh3, acc3, 0, 0, 0);
            acc3 = __builtin_amdgcn_mfma_f32_16x16x32_bf16(ah, bl3, acc3, 0, 0, 0);
        }
    }
#pragma unroll
    for (int r = 0; r < 4; ++r) {
        int row = kg * 4 + r;
        out2a[(r0 + row) * 256 + col] = acc2[r];
    }
    if (haveB) {
        float bb2 = b2b[col];
#pragma unroll
        for (int r = 0; r < 4; ++r) {
            int grow = r0 + kg * 4 + r;
            int b0 = grow >> 6, j = grow & 63;
            out2b[(b0 * 256 + col) * 64 + j] = acc3[r] + bb2;
        }
    }
}

// ---- 4. bigpass: hoisted loads; prefetch issued mid-kernel, consumed at end ----
__global__ __launch_bounds__(256) void k_bigpass(const unsigned short* __restrict__ edge_bf,
                                                 const unsigned short* __restrict__ WcT,
                                                 const float* __restrict__ bc,
                                                 const float* __restrict__ rowbias,
                                                 float* __restrict__ agg,
                                                 int mode,
                                                 const unsigned short* __restrict__ prefA,
                                                 const unsigned short* __restrict__ prefB,
                                                 int nb) {            // nb = uint4 count of B slice
    int wg = blockIdx.x;                 // 512 = b*64 + jj
    int b = wg >> 6, jj = wg & 63;
    int w = threadIdx.x >> 6, lane = threadIdx.x & 63;
    int row16 = lane & 15, kgrp = lane >> 4;

    int rstride = (mode == 0) ? 8192 : 128;
    const unsigned short* Ap = edge_bf + b * 524288 + ((mode == 0) ? jj * 128 : jj * 8192)
                             + row16 * rstride + 8 * kgrp;
    const unsigned short* Bp = WcT + (64 * w + row16) * 128 + 8 * kgrp;

    // hoist ALL fragment loads: one latency window
    bf16x8 av[4][4], bv[4][4];
#pragma unroll
    for (int kk = 0; kk < 4; ++kk) {
#pragma unroll
        for (int mi = 0; mi < 4; ++mi)
            av[mi][kk] = *(const bf16x8*)(Ap + mi * 16 * rstride + kk * 32);
#pragma unroll
        for (int ni = 0; ni < 4; ++ni)
            bv[ni][kk] = *(const bf16x8*)(Bp + ni * 2048 + kk * 32);
    }
    __builtin_amdgcn_sched_barrier(0);

    f32x4 acc[4][4];
#pragma unroll
    for (int mi = 0; mi < 4; ++mi)
#pragma unroll
        for (int ni = 0; ni < 4; ++ni) acc[mi][ni] = f32x4{0.f, 0.f, 0.f, 0.f};
#pragma unroll
    for (int kk = 0; kk < 4; ++kk)
#pragma unroll
        for (int mi = 0; mi < 4; ++mi)
#pragma unroll
            for (int ni = 0; ni < 4; ++ni)
                acc[mi][ni] = __builtin_amdgcn_mfma_f32_16x16x32_bf16(av[mi][kk], bv[ni][kk], acc[mi][ni], 0, 0, 0);

    // issue prefetch loads now (next update's weight panels, 1/64 slice);
    // their latency overlaps the epilogue, consumed at kernel end.
    int s = (blockIdx.x >> 3) & 63;
    const uint4* pa = (const uint4*)prefA + (long)s * 512;   // A slice = 512 uint4
    const uint4* pb = (const uint4*)prefB + (long)s * nb;
    uint4 pf0 = pa[threadIdx.x];
    uint4 pf1 = pa[threadIdx.x + 256];
    uint4 pf2 = pb[threadIdx.x];
    uint4 pf3, pf4;
    int big = (nb > 256);
    if (big) { pf3 = pb[threadIdx.x + 256]; pf4 = pb[threadIdx.x + 512]; }
    __builtin_amdgcn_sched_barrier(0);

    const float* rb = rowbias + (b * 64) * 256;
    float colsum[4] = {0.f, 0.f, 0.f, 0.f};
#pragma unroll
    for (int ni = 0; ni < 4; ++ni) {
        int col = 64 * w + 16 * ni + row16;
        float bch = bc[col];
#pragma unroll
        for (int mi = 0; mi < 4; ++mi) {
            int rbase = 16 * mi + 4 * kgrp;
#pragma unroll
            for (int r = 0; r < 4; ++r) {
                float v = acc[mi][ni][r] + rb[(rbase + r) * 256 + col] + bch;
                colsum[ni] += fmaxf(v, 0.f);
            }
        }
    }
#pragma unroll
    for (int ni = 0; ni < 4; ++ni) {
        colsum[ni] += __shfl_xor(colsum[ni], 16);
        colsum[ni] += __shfl_xor(colsum[ni], 32);
    }
    if (kgrp == 0) {
        float* o = agg + (b * 64 + jj) * 256 + 64 * w + row16;
#pragma unroll
        for (int ni = 0; ni < 4; ++ni) o[16 * ni] = colsum[ni] * (1.f / 64.f);
    }

    unsigned accp = pf0.x ^ pf0.w ^ pf1.y ^ pf2.z;
    if (big) accp ^= pf3.x ^ pf4.w;
    asm volatile("" :: "v"(accp));
}

// ---- 5. scores ----
__global__ __launch_bounds__(256) void k_scores(const float* __restrict__ rS,
                                                const float* __restrict__ tST,
                                                const float* __restrict__ Ws2,
                                                const float* __restrict__ bs2,
                                                float* __restrict__ scores) {
    int t = blockIdx.x * 256 + threadIdx.x;          // 32768
    int j = t & 63, i = (t >> 6) & 63, b = t >> 12;
    const float* rs = rS + (b * 64 + i) * 256;
    const float* ts = tST + b * 256 * 64 + j;
    float acc = bs2[0];
    for (int h = 0; h < 256; ++h)
        acc += fmaxf(rs[h] + ts[h * 64], 0.f) * Ws2[h];
    scores[t] = acc;
}

// ---- 6. sinkhorn: 1024 threads, v[4]/thread ----
__global__ __launch_bounds__(1024) void k_sinkhorn(const float* __restrict__ scores,
                                                   float* __restrict__ probs) {
    int b = blockIdx.x;
    int t = threadIdx.x;
    int j = t & 63, rg = t >> 6;         // 16 row-groups x 4 rows
    float v[4];
    const float* src = scores + b * 4096 + rg * 256 + j;
#pragma unroll
    for (int k = 0; k < 4; ++k) v[k] = src[k * 64];

    __shared__ float lm_s[2][16][64];
    __shared__ float ps_s[2][16][64];

    for (int it = 0; it < 10; ++it) {
#pragma unroll
        for (int k = 0; k < 4; ++k) {
            float m = v[k];
#pragma unroll
            for (int s = 1; s < 64; s <<= 1) m = fmaxf(m, __shfl_xor(m, s));
            float e = __expf(v[k] - m), ss = e;
#pragma unroll
            for (int s = 1; s < 64; s <<= 1) ss += __shfl_xor(ss, s);
            v[k] -= m + __logf(ss);
        }
        int p = it & 1;
        float lm = fmaxf(fmaxf(v[0], v[1]), fmaxf(v[2], v[3]));
        float ps = __expf(v[0] - lm) + __expf(v[1] - lm) + __expf(v[2] - lm) + __expf(v[3] - lm);
        lm_s[p][rg][j] = lm; ps_s[p][rg][j] = ps;
        __syncthreads();
        float M = lm_s[p][0][j];
#pragma unroll
        for (int g2 = 1; g2 < 16; ++g2) M = fmaxf(M, lm_s[p][g2][j]);
        float S = 0.f;
#pragma unroll
        for (int g2 = 0; g2 < 16; ++g2) S += ps_s[p][g2][j] * __expf(lm_s[p][g2][j] - M);
        float lse = M + __logf(S);
#pragma unroll
        for (int k = 0; k < 4; ++k) v[k] -= lse;
    }
    float* dst = probs + b * 4096 + rg * 256 + j;
#pragma unroll
    for (int k = 0; k < 4; ++k) dst[k * 64] = __expf(v[k]);
}

extern "C" void kernel_launch(void* const* d_in, const int* in_sizes, int n_in,
                              void* d_out, int out_size, void* d_ws, size_t ws_size,
                              hipStream_t stream) {
    const float* robot_raw = (const float*)d_in[0];
    const float* edge_raw  = (const float*)d_in[1];
    const float* Wp    = (const float*)d_in[2];
    const float* bp    = (const float*)d_in[3];
    const float* W_r2t = (const float*)d_in[4];
    const float* b_r2t = (const float*)d_in[5];
    const float* W_pt  = (const float*)d_in[6];
    const float* b_pt  = (const float*)d_in[7];
    const float* g_t   = (const float*)d_in[8];
    const float* be_t  = (const float*)d_in[9];
    const float* W_t2r = (const float*)d_in[10];
    const float* b_t2r = (const float*)d_in[11];
    const float* W_pr  = (const float*)d_in[12];
    const float* b_pr  = (const float*)d_in[13];
    const float* g_r   = (const float*)d_in[14];
    const float* be_r  = (const float*)d_in[15];
    const float* Ws1   = (const float*)d_in[16];
    const float* bs1   = (const float*)d_in[17];
    const float* Ws2   = (const float*)d_in[18];
    const float* bs2   = (const float*)d_in[19];

    char* ws = (char*)d_ws;
    unsigned short* edge_bf = (unsigned short*)(ws);            // 8,388,608
    float* traw     = (float*)(ws + 8388608);                   //   262,144
    float* robot_h  = (float*)(ws + 8650752);                   //   524,288
    float* target_h = (float*)(ws + 9175040);                   //   524,288
    unsigned short* WcT = (unsigned short*)(ws + 9699328);      //   393,216
    float* bc       = (float*)(ws + 10092544);                  //     6,144
    float* rWa      = (float*)(ws + 10098688);                  //   524,288
    float* tWa      = (float*)(ws + 10622976);                  //   524,288
    float* agg      = (float*)(ws + 11147264);                  //   524,288
    float* rS       = (float*)(ws + 11671552);                  //   524,288
    float* tST      = (float*)(ws + 12195840);                  //   524,288
    unsigned short* WTbig = (unsigned short*)(ws + 12720128);   // 3,145,728
    unsigned short* WT2   = (unsigned short*)(ws + 15865856);   // 1,835,008

    float* out    = (float*)d_out;
    float* probs  = out;            // output 0
    float* scores = out + 32768;    // output 1

    hipLaunchKernelGGL(k_prep_w, dim3(4614), dim3(256), 0, stream,
                       edge_raw, edge_bf, traw,
                       Wp, bp, W_r2t, b_r2t, W_t2r, b_t2r, W_pt, W_pr, Ws1, WcT, bc, WTbig, WT2);
    hipLaunchKernelGGL(k_proj, dim3(512), dim3(256), 0, stream,
                       robot_raw, traw, Wp, bp, W_r2t, robot_h, target_h, rWa);

    for (int l = 0; l < 3; ++l) {
        // r2t bigpass + prefetch of the target-update weights
        {
            const unsigned short* pA = WTbig + (2 * l) * 262144;       // hi+lo, 512KB
            const unsigned short* pB = WT2 + (2 * l) * 131072;
            int nb = (l == 2) ? 768 : 256;                             // l==2 covers mats 4..6
            hipLaunchKernelGGL(k_bigpass, dim3(512), dim3(256), 0, stream,
                               edge_bf, WcT + (2 * l) * 32768, bc + (2 * l) * 256, rWa, agg, 0,
                               pA, pB, nb);
        }
        const unsigned short* W2b = (l == 2) ? (WT2 + 6 * 131072) : nullptr;
        const float* b2b = (l == 2) ? bs1 : nullptr;
        float* o2b = (l == 2) ? tST : nullptr;
        hipLaunchKernelGGL(k_update_mfma, dim3(32), dim3(1024), 0, stream,
                           target_h, agg, WTbig + (2 * l) * 262144,
                           b_pt + l * 256, g_t + l * 256, be_t + l * 256,
                           WT2 + (2 * l) * 131072, tWa, W2b, b2b, o2b);
        // t2r bigpass + prefetch of the robot-update weights
        {
            const unsigned short* pA = WTbig + (2 * l + 1) * 262144;
            int m2 = (l < 2) ? (2 * l + 1) : 5;
            const unsigned short* pB = WT2 + m2 * 131072;
            hipLaunchKernelGGL(k_bigpass, dim3(512), dim3(256), 0, stream,
                               edge_bf, WcT + (2 * l + 1) * 32768, bc + (2 * l + 1) * 256, tWa, agg, 1,
                               pA, pB, 256);
        }
        const unsigned short* W2a = (l < 2) ? (WT2 + (2 * l + 1) * 131072) : (WT2 + 5 * 131072);
        float* o2a = (l < 2) ? rWa : rS;
        hipLaunchKernelGGL(k_update_mfma, dim3(32), dim3(1024), 0, stream,
                           robot_h, agg, WTbig + (2 * l + 1) * 262144,
                           b_pr + l * 256, g_r + l * 256, be_r + l * 256,
                           W2a, o2a, (const unsigned short*)nullptr, (const float*)nullptr, (float*)nullptr);
    }

    hipLaunchKernelGGL(k_scores, dim3(128), dim3(256), 0, stream, rS, tST, Ws2, bs2, scores);
    hipLaunchKernelGGL(k_sinkhorn, dim3(8), dim3(1024), 0, stream, scores, probs);
}